// Round 5
// baseline (601.638 us; speedup 1.0000x reference)
//
#include <hip/hip_runtime.h>
#include <hip/hip_bf16.h>

typedef unsigned short u16;
typedef __bf16 bf16x8 __attribute__((ext_vector_type(8)));
typedef float f32x4 __attribute__((ext_vector_type(4)));

__device__ __forceinline__ float bf2f(u16 v) { return __uint_as_float(((unsigned)v) << 16); }
__device__ __forceinline__ u16 f2bf(float f) {
  unsigned u = __float_as_uint(f);
  u += 0x7FFFu + ((u >> 16) & 1u);
  return (u16)(u >> 16);
}
__device__ __forceinline__ float gelu_exact(float x) {
  return 0.5f * x * (1.0f + erff(x * 0.70710678118654752f));
}

// async global->LDS DMA, 16B per lane; LDS dest = wave-uniform base + lane*16
__device__ __forceinline__ void async_load16(const u16* g, u16* l) {
  __builtin_amdgcn_global_load_lds((const __attribute__((address_space(1))) void*)g,
                                   (__attribute__((address_space(3))) void*)l, 16, 0, 0);
}

// ---------------- dtype sniffer (1 = bf16, 0 = fp32) ----------------
__global__ void sniff_kernel(const u16* __restrict__ x, int* __restrict__ flag) {
  int tid = threadIdx.x;  // 64
  int hits = 0;
  #pragma unroll
  for (int s = 0; s < 2; ++s) {
    float f = fabsf(bf2f(x[2 * (tid + 64 * s)]));
    hits += (f >= 0.00390625f && f <= 16.0f) ? 1 : 0;
  }
  #pragma unroll
  for (int off = 32; off; off >>= 1) hits += __shfl_xor(hits, off);
  if (tid == 0) flag[0] = (hits >= 64) ? 1 : 0;
}

// ---------------- input -> bf16 copy/convert ----------------
__global__ __launch_bounds__(256) void in2bf_kernel(const void* __restrict__ src, u16* __restrict__ dst,
                                                    int n4, const int* __restrict__ flagp) {
  int i = blockIdx.x * 256 + threadIdx.x;
  if (i >= n4) return;
  if (*flagp) {
    ((ushort4*)dst)[i] = ((const ushort4*)src)[i];
  } else {
    float4 v = ((const float4*)src)[i];
    ushort4 o; o.x = f2bf(v.x); o.y = f2bf(v.y); o.z = f2bf(v.z); o.w = f2bf(v.w);
    ((ushort4*)dst)[i] = o;
  }
}

// ---------------- all small params (LN w/b + biases) -> bf16 pool, ONE launch ----------------
__global__ __launch_bounds__(256) void small2bf_kernel(
    const void* s0, const void* s1, const void* s2, const void* s3,
    const void* s4, const void* s5, const void* s6, const void* s7,
    const void* s8, const void* s9, const void* s10, const void* s11,
    const void* s12, const void* s13,
    u16* __restrict__ dst, const int* __restrict__ flagp) {
  const void* srcs[14] = {s0, s1, s2, s3, s4, s5, s6, s7, s8, s9, s10, s11, s12, s13};
  int blk = blockIdx.x;
  int seg, u;
  if (blk < 6)       { seg = blk;            u = 0; }
  else if (blk < 9)  { seg = 6;              u = blk - 6; }
  else if (blk < 14) { seg = 7 + (blk - 9);  u = 0; }
  else if (blk < 18) { seg = 12;             u = blk - 14; }
  else               { seg = 13;             u = 0; }
  const void* src = srcs[seg];
  int i = threadIdx.x + u * 256;  // ushort4/float4 index within source
  u16* d = dst + (size_t)blk * 1024;
  if (*flagp) {
    ((ushort4*)d)[threadIdx.x] = ((const ushort4*)src)[i];
  } else {
    float4 v = ((const float4*)src)[i];
    ushort4 o; o.x = f2bf(v.x); o.y = f2bf(v.y); o.z = f2bf(v.z); o.w = f2bf(v.w);
    ((ushort4*)d)[threadIdx.x] = o;
  }
}

// ---------------- input -> fp32 copy/convert (residual stream init) ----------------
__global__ __launch_bounds__(256) void in2f32_kernel(const void* __restrict__ src, float* __restrict__ dst,
                                                     int n4, const int* __restrict__ flagp) {
  int i = blockIdx.x * 256 + threadIdx.x;
  if (i >= n4) return;
  if (*flagp) {
    ushort4 v = ((const ushort4*)src)[i];
    float4 o; o.x = bf2f(v.x); o.y = bf2f(v.y); o.z = bf2f(v.z); o.w = bf2f(v.w);
    ((float4*)dst)[i] = o;
  } else {
    ((float4*)dst)[i] = ((const float4*)src)[i];
  }
}

// ---------------- weight transpose: in [R,C] -> out [C,R] bf16, dual-dtype read ----------------
__global__ __launch_bounds__(256) void transpose_k(const void* __restrict__ in_, u16* __restrict__ out,
                                                   int R, int C, const int* __restrict__ flagp) {
  int flag = *flagp;
  __shared__ u16 tile[32][33];
  int c0 = blockIdx.x * 32, r0 = blockIdx.y * 32;
  int tx = threadIdx.x & 31, ty = threadIdx.x >> 5;
  #pragma unroll
  for (int j = 0; j < 32; j += 8) {
    size_t idx = (size_t)(r0 + ty + j) * C + c0 + tx;
    tile[ty + j][tx] = flag ? ((const u16*)in_)[idx] : f2bf(((const float*)in_)[idx]);
  }
  __syncthreads();
  #pragma unroll
  for (int j = 0; j < 32; j += 8)
    out[(size_t)(c0 + ty + j) * R + r0 + tx] = tile[tx][ty + j];
}

// ---------------- LayerNorm: fp32 in -> bf16 out, D=1024 ----------------
__global__ __launch_bounds__(256) void ln_kernel(const float* __restrict__ x,
                                                 const u16* __restrict__ w, const u16* __restrict__ b,
                                                 u16* __restrict__ out) {
  int row = blockIdx.x, tid = threadIdx.x;
  float4 v = ((const float4*)(x + (size_t)row * 1024))[tid];
  float s = v.x + v.y + v.z + v.w;
  #pragma unroll
  for (int off = 32; off; off >>= 1) s += __shfl_xor(s, off);
  __shared__ float red1[4], red2[4];
  if ((tid & 63) == 0) red1[tid >> 6] = s;
  __syncthreads();
  float mean = (red1[0] + red1[1] + red1[2] + red1[3]) * (1.0f / 1024.0f);
  float d0 = v.x - mean, d1 = v.y - mean, d2 = v.z - mean, d3 = v.w - mean;
  float vs = d0 * d0 + d1 * d1 + d2 * d2 + d3 * d3;
  #pragma unroll
  for (int off = 32; off; off >>= 1) vs += __shfl_xor(vs, off);
  if ((tid & 63) == 0) red2[tid >> 6] = vs;
  __syncthreads();
  float var = (red2[0] + red2[1] + red2[2] + red2[3]) * (1.0f / 1024.0f);
  float rs = rsqrtf(var + 1e-5f);
  int c = tid * 4;
  ushort4 o;
  o.x = f2bf(d0 * rs * bf2f(w[c + 0]) + bf2f(b[c + 0]));
  o.y = f2bf(d1 * rs * bf2f(w[c + 1]) + bf2f(b[c + 1]));
  o.z = f2bf(d2 * rs * bf2f(w[c + 2]) + bf2f(b[c + 2]));
  o.w = f2bf(d3 * rs * bf2f(w[c + 3]) + bf2f(b[c + 3]));
  ((ushort4*)(out + (size_t)row * 1024))[tid] = o;
}

// ---------------- TN GEMM: C[M,N] = A[M,K] @ Bt[N,K]^T + bias, bf16 MFMA ----------------
// (unchanged from round 3 — proven at 595.7us)
template <int MODE, int TN>
__global__ __launch_bounds__(256) void gemm_tn(const u16* __restrict__ A, const u16* __restrict__ Bt,
                                               const u16* __restrict__ bias,
                                               const float* __restrict__ resid_in, float* __restrict__ resid_out,
                                               void* __restrict__ outp, int M, int N, int K,
                                               const int* __restrict__ flagp) {
  constexpr int NI = TN / 32;
  __shared__ __align__(16) u16 As[128 * 64];
  __shared__ __align__(16) u16 Bs[TN * 64];

  int nwg = gridDim.x * gridDim.y;
  int bid = blockIdx.y * gridDim.x + blockIdx.x;
  int chunk = nwg >> 3;
  int s = (bid & 7) * chunk + (bid >> 3);
  int bx = s % gridDim.x, by = s / gridDim.x;

  int n0 = bx * TN, m0 = by * 128;
  int tid = threadIdx.x;
  int lane = tid & 63, w = tid >> 6;
  int wm = w & 1, wn = w >> 1;
  int quad = lane >> 4, l15 = lane & 15;
  int sw = l15 & 7;
  int flag = (MODE == 3) ? *flagp : 0;
  f32x4 acc[4][NI];
  #pragma unroll
  for (int i = 0; i < 4; i++)
    #pragma unroll
    for (int j = 0; j < NI; j++) acc[i][j] = (f32x4){0.f, 0.f, 0.f, 0.f};

  int srow8 = lane >> 3;
  int scol = ((lane & 7) ^ srow8) * 8;
  const u16* Abase = A + (size_t)(m0 + srow8) * K + scol;
  const u16* Bbase = Bt + (size_t)(n0 + srow8) * K + scol;

  for (int k0 = 0; k0 < K; k0 += 64) {
    #pragma unroll
    for (int j = 0; j < 4; ++j) {
      int r0 = (w * 4 + j) * 8;
      async_load16(Abase + (size_t)r0 * K + k0, &As[r0 * 64]);
    }
    #pragma unroll
    for (int j = 0; j < TN / 32; ++j) {
      int r0 = (w * (TN / 32) + j) * 8;
      async_load16(Bbase + (size_t)r0 * K + k0, &Bs[r0 * 64]);
    }
    __syncthreads();
    #pragma unroll
    for (int kk = 0; kk < 64; kk += 32) {
      int cbase = (kk >> 3) + quad;
      int slot = (cbase ^ sw) << 3;
      bf16x8 af[4], bfr[NI];
      #pragma unroll
      for (int i = 0; i < 4; i++)
        af[i] = *(const bf16x8*)&As[(wm * 64 + i * 16 + l15) * 64 + slot];
      #pragma unroll
      for (int j = 0; j < NI; j++)
        bfr[j] = *(const bf16x8*)&Bs[(wn * (TN / 2) + j * 16 + l15) * 64 + slot];
      #pragma unroll
      for (int mi = 0; mi < 4; mi++)
        #pragma unroll
        for (int ni = 0; ni < NI; ni++)
          acc[mi][ni] = __builtin_amdgcn_mfma_f32_16x16x32_bf16(af[mi], bfr[ni], acc[mi][ni], 0, 0, 0);
    }
    __syncthreads();
  }

  int col_base = n0 + wn * (TN / 2), row_base = m0 + wm * 64;
  #pragma unroll
  for (int mi = 0; mi < 4; mi++) {
    #pragma unroll
    for (int ni = 0; ni < NI; ni++) {
      int col = col_base + ni * 16 + l15;
      float bv = bf2f(bias[col]);
      #pragma unroll
      for (int r = 0; r < 4; r++) {
        int row = row_base + mi * 16 + quad * 4 + r;
        float vv = acc[mi][ni][r] + bv;
        size_t idx = (size_t)row * N + col;
        if (MODE == 0) ((u16*)outp)[idx] = f2bf(vv);
        else if (MODE == 1) resid_out[idx] = resid_in[idx] + vv;
        else if (MODE == 2) ((u16*)outp)[idx] = f2bf(gelu_exact(vv));
        else {
          float ov = resid_in[idx] + vv;
          if (flag) ((u16*)outp)[idx] = f2bf(ov);
          else ((float*)outp)[idx] = ov;
        }
      }
    }
  }
}

// ---------------- MFMA flash attention, HD=64, conflict-free + deep-prefetch ----------------
// Round-4 analysis: conflicts were 0 but time flat -> K DMA latency was exposed
// (issued and awaited in the same iteration), and the causal "balance" permute
// was XCD-hostile (linear id % 8 = blockIdx.x % 8 picks the XCD; qi=0 and qi=15
// landed on different XCDs -> 4.7x per-XCD imbalance, 14% occupancy tail).
// Now: Ks double-buffered; K(t+1) DMA + V(t+1) reg loads issued AFTER this
// tile's Vt stores -> a full compute phase covers their latency. The Vt stores'
// compiler-inserted wait on V(t) (VMEM retires in order; K(t) is older) also
// guarantees K(t) is in LDS -- no explicit mid-loop vmcnt drain at all.
// Q is staged into Ps (per-wave region w: rows w*16..w*16+15 exactly = Ps[w])
// so the extra Ks buffer costs no LDS. Causal: qi = x<8 ? x : 23-x pairs tile
// counts (x+1) and (16-x) on the SAME XCD -> every XCD gets 17 tiles per y.
__global__ __launch_bounds__(256) void attn_mfma(const u16* __restrict__ Q, const u16* __restrict__ K,
                                                 const u16* __restrict__ V, u16* __restrict__ O,
                                                 int T, int S, int qstride, int kstride, int causal) {
  int bh = blockIdx.y, b = bh >> 4, h = bh & 15;
  int gx = gridDim.x, xi = blockIdx.x;
  int qi = causal ? ((xi < (gx >> 1)) ? xi : (gx + (gx >> 1) - 1 - xi)) : xi;
  int qt = qi * 64;

  const u16* Qb = Q + (size_t)b * T * qstride + h * 64;
  const u16* Kb = K + (size_t)b * S * kstride + h * 64;
  const u16* Vb = V + (size_t)b * S * kstride + h * 64;
  u16* Ob = O + (size_t)b * T * 1024 + h * 64;

  int tid = threadIdx.x, lane = tid & 63, w = tid >> 6;
  int quad = lane >> 4, l15 = lane & 15;

  __shared__ __align__(16) u16 Ks[2][64 * 64];
  __shared__ __align__(16) u16 Vt[64 * 64];
  __shared__ __align__(16) u16 Ps[4][16 * 64];
  u16* Psq = &Ps[0][0];  // Q staging alias (wave w touches only rows w*16..+15 = Ps[w])

  int srow8 = lane >> 3;
  int scol = ((lane & 7) ^ srow8) * 8;

  // ---- prologue: Q DMA -> Psq, K(0) DMA -> Ks[0], V(0) -> regs ----
  #pragma unroll
  for (int j = 0; j < 2; ++j) {
    int r0 = (w * 2 + j) * 8;
    async_load16(Qb + (size_t)(qt + r0 + srow8) * qstride + scol, &Psq[r0 * 64]);
  }
  #pragma unroll
  for (int j = 0; j < 2; ++j) {
    int r0 = (w * 2 + j) * 8;
    async_load16(Kb + (size_t)(r0 + srow8) * kstride + scol, &Ks[0][r0 * 64]);
  }
  asm volatile("" ::: "memory");
  uint4 v0 = *(const uint4*)&Vb[(size_t)lane * kstride + w * 16];
  uint4 v1 = *(const uint4*)&Vb[(size_t)lane * kstride + w * 16 + 8];
  asm volatile("s_waitcnt vmcnt(4)" ::: "memory");  // Q landed; K(0)/V(0) still flying
  __builtin_amdgcn_s_barrier();

  int qrow = w * 16 + l15;
  bf16x8 qfrag[2];
  #pragma unroll
  for (int c = 0; c < 2; ++c)
    qfrag[c] = *(const bf16x8*)&Psq[qrow * 64 + (((c * 4 + quad) ^ (l15 & 7)) << 3)];
  asm volatile("s_waitcnt lgkmcnt(0)" ::: "memory");  // qfrag in regs before Ps reuse

  float m_i[4], l_i[4];
  f32x4 oacc[4];
  #pragma unroll
  for (int r = 0; r < 4; ++r) { m_i[r] = -1e30f; l_i[r] = 0.f; }
  #pragma unroll
  for (int ni = 0; ni < 4; ++ni) oacc[ni] = (f32x4){0.f, 0.f, 0.f, 0.f};

  int nk = causal ? (qi + 1) * 64 : S;
  int tg0 = qt + w * 16 + quad * 4;

  for (int s0 = 0; s0 < nk; s0 += 64) {
    int cur = (s0 >> 6) & 1;
    __builtin_amdgcn_s_barrier();  // all waves done with prev tile's LDS reads
    // Vt stores: compiler waits V(t) (in-order VMEM retire => K(t) also done)
    union { uint4 u[2]; u16 e[16]; } vv; vv.u[0] = v0; vv.u[1] = v1;
    #pragma unroll
    for (int j = 0; j < 16; ++j) {
      int d = w * 16 + j;
      Vt[d * 64 + ((((lane >> 3) ^ (j & 7)) << 3) | (lane & 7))] = vv.e[j];
    }
    // prefetch next tile: K DMA into other buffer, V into regs
    if (s0 + 64 < nk) {
      #pragma unroll
      for (int j = 0; j < 2; ++j) {
        int r0 = (w * 2 + j) * 8;
        async_load16(Kb + (size_t)(s0 + 64 + r0 + srow8) * kstride + scol, &Ks[cur ^ 1][r0 * 64]);
      }
      asm volatile("" ::: "memory");
      v0 = *(const uint4*)&Vb[(size_t)(s0 + 64 + lane) * kstride + w * 16];
      v1 = *(const uint4*)&Vb[(size_t)(s0 + 64 + lane) * kstride + w * 16 + 8];
    }
    asm volatile("s_waitcnt lgkmcnt(0)" ::: "memory");  // Vt committed
    __builtin_amdgcn_s_barrier();

    // ---- QK^T ----
    f32x4 sacc[4];
    #pragma unroll
    for (int ni = 0; ni < 4; ++ni) sacc[ni] = (f32x4){0.f, 0.f, 0.f, 0.f};
    __builtin_amdgcn_s_setprio(1);
    #pragma unroll
    for (int c = 0; c < 2; ++c) {
      #pragma unroll
      for (int ni = 0; ni < 4; ++ni) {
        bf16x8 kf = *(const bf16x8*)&Ks[cur][(ni * 16 + l15) * 64 + (((c * 4 + quad) ^ (l15 & 7)) << 3)];
        sacc[ni] = __builtin_amdgcn_mfma_f32_16x16x32_bf16(qfrag[c], kf, sacc[ni], 0, 0, 0);
      }
    }
    __builtin_amdgcn_s_setprio(0);

    #pragma unroll
    for (int ni = 0; ni < 4; ++ni)
      #pragma unroll
      for (int r = 0; r < 4; ++r) sacc[ni][r] *= 0.125f;
    if (causal && s0 + 63 > qt + w * 16) {  // wave-uniform: only diagonal tiles
      #pragma unroll
      for (int ni = 0; ni < 4; ++ni) {
        int key = s0 + ni * 16 + l15;
        #pragma unroll
        for (int r = 0; r < 4; ++r)
          if (key > tg0 + r) sacc[ni][r] = -1e30f;
      }
    }

    // ---- online softmax ----
    float mnew[4], alpha[4], psum[4];
    #pragma unroll
    for (int r = 0; r < 4; ++r) {
      float mx = fmaxf(fmaxf(sacc[0][r], sacc[1][r]), fmaxf(sacc[2][r], sacc[3][r]));
      #pragma unroll
      for (int off = 1; off < 16; off <<= 1) mx = fmaxf(mx, __shfl_xor(mx, off));
      mnew[r] = fmaxf(m_i[r], mx);
      alpha[r] = __expf(m_i[r] - mnew[r]);
      m_i[r] = mnew[r];
      psum[r] = 0.f;
    }
    #pragma unroll
    for (int ni = 0; ni < 4; ++ni) {
      #pragma unroll
      for (int r = 0; r < 4; ++r) {
        float p = __expf(sacc[ni][r] - mnew[r]);
        psum[r] += p;
        int row = quad * 4 + r;
        int blk = (ni * 2 + (l15 >> 3)) ^ (row & 7);
        Ps[w][row * 64 + (blk << 3) + (l15 & 7)] = f2bf(p);
      }
    }
    #pragma unroll
    for (int r = 0; r < 4; ++r) {
      float ps = psum[r];
      #pragma unroll
      for (int off = 1; off < 16; off <<= 1) ps += __shfl_xor(ps, off);
      l_i[r] = l_i[r] * alpha[r] + ps;
    }

    // ---- PV ----
    bf16x8 pfrag[2];
    #pragma unroll
    for (int c = 0; c < 2; ++c)
      pfrag[c] = *(const bf16x8*)&Ps[w][l15 * 64 + (((c * 4 + quad) ^ (l15 & 7)) << 3)];
    #pragma unroll
    for (int ni = 0; ni < 4; ++ni)
      #pragma unroll
      for (int r = 0; r < 4; ++r) oacc[ni][r] *= alpha[r];
    __builtin_amdgcn_s_setprio(1);
    #pragma unroll
    for (int c = 0; c < 2; ++c) {
      #pragma unroll
      for (int ni = 0; ni < 4; ++ni) {
        bf16x8 vf = *(const bf16x8*)&Vt[(ni * 16 + l15) * 64 + (((c * 4 + quad) ^ (l15 & 7)) << 3)];
        oacc[ni] = __builtin_amdgcn_mfma_f32_16x16x32_bf16(pfrag[c], vf, oacc[ni], 0, 0, 0);
      }
    }
    __builtin_amdgcn_s_setprio(0);
  }

  #pragma unroll
  for (int ni = 0; ni < 4; ++ni) {
    #pragma unroll
    for (int r = 0; r < 4; ++r) {
      int t = tg0 + r;
      int d = ni * 16 + l15;
      Ob[(size_t)t * 1024 + d] = f2bf(oacc[ni][r] / l_i[r]);
    }
  }
}

extern "C" void kernel_launch(void* const* d_in, const int* in_sizes, int n_in,
                              void* d_out, int out_size, void* d_ws, size_t ws_size,
                              hipStream_t stream) {
  const void* x_in   = d_in[0];
  const void* enc_in = d_in[1];
  const void* ln1_w = d_in[4];  const void* ln1_b = d_in[5];
  const void* qkv_w = d_in[6];  const void* qkv_b = d_in[7];
  const void* proj_w = d_in[8]; const void* proj_b = d_in[9];
  const void* ln2_w = d_in[10]; const void* ln2_b = d_in[11];
  const void* q_w = d_in[12];   const void* q_b = d_in[13];
  const void* k_w = d_in[14];   const void* k_b = d_in[15];
  const void* v_w = d_in[16];   const void* v_b = d_in[17];
  const void* out_w = d_in[18]; const void* out_b = d_in[19];
  const void* ln3_w = d_in[20]; const void* ln3_b = d_in[21];
  const void* mlp1_w = d_in[22]; const void* mlp1_b = d_in[23];
  const void* mlp2_w = d_in[24]; const void* mlp2_b = d_in[25];

  char* ws = (char*)d_ws;
  size_t off = 0;
  auto alloc = [&](size_t bytes) { char* p = ws + off; off += (bytes + 255) & ~(size_t)255; return p; };
  float* xf   = (float*)alloc(4096ull * 1024 * 4);
  u16* hb     = (u16*)alloc(4096ull * 1024 * 2);
  u16* big    = (u16*)alloc(4096ull * 4096 * 2);
  u16* wT     = (u16*)alloc(3072ull * 1024 * 2);
  u16* encb   = (u16*)alloc(2304ull * 768 * 2);
  u16* pool   = (u16*)alloc(20480ull * 2);
  int* flag   = (int*)alloc(256);
  (void)ws_size;

  u16* q_bf = big;
  u16* k_bf = big + 4096ull * 1024;
  u16* v_bf = big + (4096ull + 2304) * 1024;

  u16 *p_ln1w = pool, *p_ln1b = pool + 1024, *p_ln2w = pool + 2048, *p_ln2b = pool + 3072;
  u16 *p_ln3w = pool + 4096, *p_ln3b = pool + 5120;
  u16 *p_qkvb = pool + 6144, *p_projb = pool + 9216, *p_qb = pool + 10240, *p_kb = pool + 11264;
  u16 *p_vb = pool + 12288, *p_outb = pool + 13312, *p_m1b = pool + 14336, *p_m2b = pool + 18432;

  // ---- dtype sniff + input conversion ----
  sniff_kernel<<<1, 64, 0, stream>>>((const u16*)x_in, flag);
  in2f32_kernel<<<4096, 256, 0, stream>>>(x_in, xf, 1048576, flag);
  in2bf_kernel<<<1728, 256, 0, stream>>>(enc_in, encb, 442368, flag);
  small2bf_kernel<<<19, 256, 0, stream>>>(ln1_w, ln1_b, ln2_w, ln2_b, ln3_w, ln3_b,
                                          qkv_b, proj_b, q_b, k_b, v_b, out_b,
                                          mlp1_b, mlp2_b, pool, flag);

  // ---- self-attention block ----
  ln_kernel<<<4096, 256, 0, stream>>>(xf, p_ln1w, p_ln1b, hb);
  transpose_k<<<dim3(96, 32), 256, 0, stream>>>(qkv_w, wT, 1024, 3072, flag);
  gemm_tn<0, 128><<<dim3(24, 32), 256, 0, stream>>>(hb, wT, p_qkvb, nullptr, nullptr, big, 4096, 3072, 1024, flag);
  attn_mfma<<<dim3(16, 64), 256, 0, stream>>>(big, big + 1024, big + 2048, hb, 1024, 1024, 3072, 3072, 1);
  transpose_k<<<dim3(32, 32), 256, 0, stream>>>(proj_w, wT, 1024, 1024, flag);
  gemm_tn<1, 64><<<dim3(16, 32), 256, 0, stream>>>(hb, wT, p_projb, xf, xf, nullptr, 4096, 1024, 1024, flag);

  // ---- cross-attention block ----
  ln_kernel<<<4096, 256, 0, stream>>>(xf, p_ln2w, p_ln2b, hb);
  transpose_k<<<dim3(32, 32), 256, 0, stream>>>(q_w, wT, 1024, 1024, flag);
  gemm_tn<0, 64><<<dim3(16, 32), 256, 0, stream>>>(hb, wT, p_qb, nullptr, nullptr, q_bf, 4096, 1024, 1024, flag);
  transpose_k<<<dim3(32, 24), 256, 0, stream>>>(k_w, wT, 768, 1024, flag);
  gemm_tn<0, 64><<<dim3(16, 18), 256, 0, stream>>>(encb, wT, p_kb, nullptr, nullptr, k_bf, 2304, 1024, 768, flag);
  transpose_k<<<dim3(32, 24), 256, 0, stream>>>(v_w, wT, 768, 1024, flag);
  gemm_tn<0, 64><<<dim3(16, 18), 256, 0, stream>>>(encb, wT, p_vb, nullptr, nullptr, v_bf, 2304, 1024, 768, flag);
  attn_mfma<<<dim3(16, 64), 256, 0, stream>>>(q_bf, k_bf, v_bf, hb, 1024, 576, 1024, 1024, 0);
  transpose_k<<<dim3(32, 32), 256, 0, stream>>>(out_w, wT, 1024, 1024, flag);
  gemm_tn<1, 64><<<dim3(16, 32), 256, 0, stream>>>(hb, wT, p_outb, xf, xf, nullptr, 4096, 1024, 1024, flag);

  // ---- MLP block ----
  ln_kernel<<<4096, 256, 0, stream>>>(xf, p_ln3w, p_ln3b, hb);
  transpose_k<<<dim3(128, 32), 256, 0, stream>>>(mlp1_w, wT, 1024, 4096, flag);
  gemm_tn<2, 128><<<dim3(32, 32), 256, 0, stream>>>(hb, wT, p_m1b, nullptr, nullptr, big, 4096, 4096, 1024, flag);
  transpose_k<<<dim3(32, 128), 256, 0, stream>>>(mlp2_w, wT, 4096, 1024, flag);
  gemm_tn<3, 64><<<dim3(16, 32), 256, 0, stream>>>(big, wT, p_m2b, xf, nullptr, d_out, 4096, 1024, 4096, flag);
}

// Round 6
// 577.487 us; speedup vs baseline: 1.0418x; 1.0418x over previous
//
#include <hip/hip_runtime.h>
#include <hip/hip_bf16.h>

typedef unsigned short u16;
typedef __bf16 bf16x8 __attribute__((ext_vector_type(8)));
typedef float f32x4 __attribute__((ext_vector_type(4)));

__device__ __forceinline__ float bf2f(u16 v) { return __uint_as_float(((unsigned)v) << 16); }
__device__ __forceinline__ u16 f2bf(float f) {
  unsigned u = __float_as_uint(f);
  u += 0x7FFFu + ((u >> 16) & 1u);
  return (u16)(u >> 16);
}
__device__ __forceinline__ float gelu_exact(float x) {
  return 0.5f * x * (1.0f + erff(x * 0.70710678118654752f));
}

// async global->LDS DMA, 16B per lane; LDS dest = wave-uniform base + lane*16
__device__ __forceinline__ void async_load16(const u16* g, u16* l) {
  __builtin_amdgcn_global_load_lds((const __attribute__((address_space(1))) void*)g,
                                   (__attribute__((address_space(3))) void*)l, 16, 0, 0);
}

// ---------------- dtype sniffer (1 = bf16, 0 = fp32) ----------------
__global__ void sniff_kernel(const u16* __restrict__ x, int* __restrict__ flag) {
  int tid = threadIdx.x;  // 64
  int hits = 0;
  #pragma unroll
  for (int s = 0; s < 2; ++s) {
    float f = fabsf(bf2f(x[2 * (tid + 64 * s)]));
    hits += (f >= 0.00390625f && f <= 16.0f) ? 1 : 0;
  }
  #pragma unroll
  for (int off = 32; off; off >>= 1) hits += __shfl_xor(hits, off);
  if (tid == 0) flag[0] = (hits >= 64) ? 1 : 0;
}

// ---------------- input -> bf16 copy/convert ----------------
__global__ __launch_bounds__(256) void in2bf_kernel(const void* __restrict__ src, u16* __restrict__ dst,
                                                    int n4, const int* __restrict__ flagp) {
  int i = blockIdx.x * 256 + threadIdx.x;
  if (i >= n4) return;
  if (*flagp) {
    ((ushort4*)dst)[i] = ((const ushort4*)src)[i];
  } else {
    float4 v = ((const float4*)src)[i];
    ushort4 o; o.x = f2bf(v.x); o.y = f2bf(v.y); o.z = f2bf(v.z); o.w = f2bf(v.w);
    ((ushort4*)dst)[i] = o;
  }
}

// ---------------- all small params (LN w/b + biases) -> bf16 pool, ONE launch ----------------
__global__ __launch_bounds__(256) void small2bf_kernel(
    const void* s0, const void* s1, const void* s2, const void* s3,
    const void* s4, const void* s5, const void* s6, const void* s7,
    const void* s8, const void* s9, const void* s10, const void* s11,
    const void* s12, const void* s13,
    u16* __restrict__ dst, const int* __restrict__ flagp) {
  const void* srcs[14] = {s0, s1, s2, s3, s4, s5, s6, s7, s8, s9, s10, s11, s12, s13};
  int blk = blockIdx.x;
  int seg, u;
  if (blk < 6)       { seg = blk;            u = 0; }
  else if (blk < 9)  { seg = 6;              u = blk - 6; }
  else if (blk < 14) { seg = 7 + (blk - 9);  u = 0; }
  else if (blk < 18) { seg = 12;             u = blk - 14; }
  else               { seg = 13;             u = 0; }
  const void* src = srcs[seg];
  int i = threadIdx.x + u * 256;  // ushort4/float4 index within source
  u16* d = dst + (size_t)blk * 1024;
  if (*flagp) {
    ((ushort4*)d)[threadIdx.x] = ((const ushort4*)src)[i];
  } else {
    float4 v = ((const float4*)src)[i];
    ushort4 o; o.x = f2bf(v.x); o.y = f2bf(v.y); o.z = f2bf(v.z); o.w = f2bf(v.w);
    ((ushort4*)d)[threadIdx.x] = o;
  }
}

// ---------------- input -> fp32 copy/convert (residual stream init) ----------------
__global__ __launch_bounds__(256) void in2f32_kernel(const void* __restrict__ src, float* __restrict__ dst,
                                                     int n4, const int* __restrict__ flagp) {
  int i = blockIdx.x * 256 + threadIdx.x;
  if (i >= n4) return;
  if (*flagp) {
    ushort4 v = ((const ushort4*)src)[i];
    float4 o; o.x = bf2f(v.x); o.y = bf2f(v.y); o.z = bf2f(v.z); o.w = bf2f(v.w);
    ((float4*)dst)[i] = o;
  } else {
    ((float4*)dst)[i] = ((const float4*)src)[i];
  }
}

// ---------------- weight transpose: in [R,C] -> out [C,R] bf16, dual-dtype read ----------------
__global__ __launch_bounds__(256) void transpose_k(const void* __restrict__ in_, u16* __restrict__ out,
                                                   int R, int C, const int* __restrict__ flagp) {
  int flag = *flagp;
  __shared__ u16 tile[32][33];
  int c0 = blockIdx.x * 32, r0 = blockIdx.y * 32;
  int tx = threadIdx.x & 31, ty = threadIdx.x >> 5;
  #pragma unroll
  for (int j = 0; j < 32; j += 8) {
    size_t idx = (size_t)(r0 + ty + j) * C + c0 + tx;
    tile[ty + j][tx] = flag ? ((const u16*)in_)[idx] : f2bf(((const float*)in_)[idx]);
  }
  __syncthreads();
  #pragma unroll
  for (int j = 0; j < 32; j += 8)
    out[(size_t)(c0 + ty + j) * R + r0 + tx] = tile[tx][ty + j];
}

// ---------------- LayerNorm: fp32 in -> bf16 out, D=1024 ----------------
__global__ __launch_bounds__(256) void ln_kernel(const float* __restrict__ x,
                                                 const u16* __restrict__ w, const u16* __restrict__ b,
                                                 u16* __restrict__ out) {
  int row = blockIdx.x, tid = threadIdx.x;
  float4 v = ((const float4*)(x + (size_t)row * 1024))[tid];
  float s = v.x + v.y + v.z + v.w;
  #pragma unroll
  for (int off = 32; off; off >>= 1) s += __shfl_xor(s, off);
  __shared__ float red1[4], red2[4];
  if ((tid & 63) == 0) red1[tid >> 6] = s;
  __syncthreads();
  float mean = (red1[0] + red1[1] + red1[2] + red1[3]) * (1.0f / 1024.0f);
  float d0 = v.x - mean, d1 = v.y - mean, d2 = v.z - mean, d3 = v.w - mean;
  float vs = d0 * d0 + d1 * d1 + d2 * d2 + d3 * d3;
  #pragma unroll
  for (int off = 32; off; off >>= 1) vs += __shfl_xor(vs, off);
  if ((tid & 63) == 0) red2[tid >> 6] = vs;
  __syncthreads();
  float var = (red2[0] + red2[1] + red2[2] + red2[3]) * (1.0f / 1024.0f);
  float rs = rsqrtf(var + 1e-5f);
  int c = tid * 4;
  ushort4 o;
  o.x = f2bf(d0 * rs * bf2f(w[c + 0]) + bf2f(b[c + 0]));
  o.y = f2bf(d1 * rs * bf2f(w[c + 1]) + bf2f(b[c + 1]));
  o.z = f2bf(d2 * rs * bf2f(w[c + 2]) + bf2f(b[c + 2]));
  o.w = f2bf(d3 * rs * bf2f(w[c + 3]) + bf2f(b[c + 3]));
  ((ushort4*)(out + (size_t)row * 1024))[tid] = o;
}

// ---------------- TN GEMM: C[M,N] = A[M,K] @ Bt[N,K]^T + bias, bf16 MFMA ----------------
// (unchanged from round 3 — proven)
template <int MODE, int TN>
__global__ __launch_bounds__(256) void gemm_tn(const u16* __restrict__ A, const u16* __restrict__ Bt,
                                               const u16* __restrict__ bias,
                                               const float* __restrict__ resid_in, float* __restrict__ resid_out,
                                               void* __restrict__ outp, int M, int N, int K,
                                               const int* __restrict__ flagp) {
  constexpr int NI = TN / 32;
  __shared__ __align__(16) u16 As[128 * 64];
  __shared__ __align__(16) u16 Bs[TN * 64];

  int nwg = gridDim.x * gridDim.y;
  int bid = blockIdx.y * gridDim.x + blockIdx.x;
  int chunk = nwg >> 3;
  int s = (bid & 7) * chunk + (bid >> 3);
  int bx = s % gridDim.x, by = s / gridDim.x;

  int n0 = bx * TN, m0 = by * 128;
  int tid = threadIdx.x;
  int lane = tid & 63, w = tid >> 6;
  int wm = w & 1, wn = w >> 1;
  int quad = lane >> 4, l15 = lane & 15;
  int sw = l15 & 7;
  int flag = (MODE == 3) ? *flagp : 0;
  f32x4 acc[4][NI];
  #pragma unroll
  for (int i = 0; i < 4; i++)
    #pragma unroll
    for (int j = 0; j < NI; j++) acc[i][j] = (f32x4){0.f, 0.f, 0.f, 0.f};

  int srow8 = lane >> 3;
  int scol = ((lane & 7) ^ srow8) * 8;
  const u16* Abase = A + (size_t)(m0 + srow8) * K + scol;
  const u16* Bbase = Bt + (size_t)(n0 + srow8) * K + scol;

  for (int k0 = 0; k0 < K; k0 += 64) {
    #pragma unroll
    for (int j = 0; j < 4; ++j) {
      int r0 = (w * 4 + j) * 8;
      async_load16(Abase + (size_t)r0 * K + k0, &As[r0 * 64]);
    }
    #pragma unroll
    for (int j = 0; j < TN / 32; ++j) {
      int r0 = (w * (TN / 32) + j) * 8;
      async_load16(Bbase + (size_t)r0 * K + k0, &Bs[r0 * 64]);
    }
    __syncthreads();
    #pragma unroll
    for (int kk = 0; kk < 64; kk += 32) {
      int cbase = (kk >> 3) + quad;
      int slot = (cbase ^ sw) << 3;
      bf16x8 af[4], bfr[NI];
      #pragma unroll
      for (int i = 0; i < 4; i++)
        af[i] = *(const bf16x8*)&As[(wm * 64 + i * 16 + l15) * 64 + slot];
      #pragma unroll
      for (int j = 0; j < NI; j++)
        bfr[j] = *(const bf16x8*)&Bs[(wn * (TN / 2) + j * 16 + l15) * 64 + slot];
      #pragma unroll
      for (int mi = 0; mi < 4; mi++)
        #pragma unroll
        for (int ni = 0; ni < NI; ni++)
          acc[mi][ni] = __builtin_amdgcn_mfma_f32_16x16x32_bf16(af[mi], bfr[ni], acc[mi][ni], 0, 0, 0);
    }
    __syncthreads();
  }

  int col_base = n0 + wn * (TN / 2), row_base = m0 + wm * 64;
  #pragma unroll
  for (int mi = 0; mi < 4; mi++) {
    #pragma unroll
    for (int ni = 0; ni < NI; ni++) {
      int col = col_base + ni * 16 + l15;
      float bv = bf2f(bias[col]);
      #pragma unroll
      for (int r = 0; r < 4; r++) {
        int row = row_base + mi * 16 + quad * 4 + r;
        float vv = acc[mi][ni][r] + bv;
        size_t idx = (size_t)row * N + col;
        if (MODE == 0) ((u16*)outp)[idx] = f2bf(vv);
        else if (MODE == 1) resid_out[idx] = resid_in[idx] + vv;
        else if (MODE == 2) ((u16*)outp)[idx] = f2bf(gelu_exact(vv));
        else {
          float ov = resid_in[idx] + vv;
          if (flag) ((u16*)outp)[idx] = f2bf(ov);
          else ((float*)outp)[idx] = ov;
        }
      }
    }
  }
}

// ---------------- MFMA flash attention, HD=64, QBLK=128 ----------------
// Round-5 post-mortem: deep K-prefetch regressed (84us) + one 31ms outlier ->
// reverted to round-4's proven single-Ks flow (73.6us stable, 0 conflicts).
// Remaining bottleneck is the latency of the per-tile serial chain (VALUBusy
// 25%, MfmaUtil 4.5%, CU ~70% idle). Fix: QBLK=128 -- each wave owns TWO 16-row
// blocks (rb=0,1). Per-tile fixed overhead (2 barriers, K DMA+wait, Vt
// transpose, V prefetch) amortizes over 2x compute, and the two independent
// softmax chains double ILP to fill latency. Causal: rb=0 skipped entirely
// once s0 >= qt+64 (block-uniform). XCD balance: XCD = blockIdx.x (gx=8, linear
// id % 8 = x); qi=(x+y)&7 gives every XCD all causal depths across y.
// LDS 32KB: Ks 8 + Vt 8 + Ps 16 (Q stages through Ps = exactly 128 rows).
__global__ __launch_bounds__(256, 2) void attn_mfma(const u16* __restrict__ Q, const u16* __restrict__ K,
                                                    const u16* __restrict__ V, u16* __restrict__ O,
                                                    int T, int S, int qstride, int kstride, int causal) {
  int bh = blockIdx.y, b = bh >> 4, h = bh & 15;
  int x = blockIdx.x, y = blockIdx.y;
  int qi = causal ? ((x + y) & 7) : x;
  int qt = qi * 128;

  const u16* Qb = Q + (size_t)b * T * qstride + h * 64;
  const u16* Kb = K + (size_t)b * S * kstride + h * 64;
  const u16* Vb = V + (size_t)b * S * kstride + h * 64;
  u16* Ob = O + (size_t)b * T * 1024 + h * 64;

  int tid = threadIdx.x, lane = tid & 63, w = tid >> 6;
  int quad = lane >> 4, l15 = lane & 15;

  __shared__ __align__(16) u16 Ks[64 * 64];
  __shared__ __align__(16) u16 Vt[64 * 64];
  __shared__ __align__(16) u16 Ps[128 * 64];  // per-wave 32 rows (2 rb x 16); doubles as Q staging

  int srow8 = lane >> 3;
  int scol = ((lane & 7) ^ srow8) * 8;

  // ---- prologue: Q DMA -> Ps (128 rows), V(0) -> regs ----
  #pragma unroll
  for (int j = 0; j < 4; ++j) {
    int r0 = (w * 4 + j) * 8;
    async_load16(Qb + (size_t)(qt + r0 + srow8) * qstride + scol, &Ps[r0 * 64]);
  }
  asm volatile("" ::: "memory");
  uint4 v0 = *(const uint4*)&Vb[(size_t)lane * kstride + w * 16];
  uint4 v1 = *(const uint4*)&Vb[(size_t)lane * kstride + w * 16 + 8];
  asm volatile("s_waitcnt vmcnt(2)" ::: "memory");  // Q's 4 DMA retired; V(0) flying
  __builtin_amdgcn_s_barrier();

  bf16x8 qfrag[2][2];
  #pragma unroll
  for (int rb = 0; rb < 2; ++rb)
    #pragma unroll
    for (int c = 0; c < 2; ++c)
      qfrag[rb][c] = *(const bf16x8*)&Ps[(rb * 64 + w * 16 + l15) * 64 + (((c * 4 + quad) ^ (l15 & 7)) << 3)];
  asm volatile("s_waitcnt lgkmcnt(0)" ::: "memory");  // qfrags in regs before Ps reuse

  float m_i[2][4], l_i[2][4];
  f32x4 oacc[2][4];
  #pragma unroll
  for (int rb = 0; rb < 2; ++rb) {
    #pragma unroll
    for (int r = 0; r < 4; ++r) { m_i[rb][r] = -1e30f; l_i[rb][r] = 0.f; }
    #pragma unroll
    for (int ni = 0; ni < 4; ++ni) oacc[rb][ni] = (f32x4){0.f, 0.f, 0.f, 0.f};
  }

  int nk = causal ? (qt + 128) : S;

  for (int s0 = 0; s0 < nk; s0 += 64) {
    __builtin_amdgcn_s_barrier();  // all waves done with prev tile's LDS reads
    // K(t) DMA (counted waits below keep it in flight during Vt stores)
    #pragma unroll
    for (int j = 0; j < 2; ++j) {
      int r0 = (w * 2 + j) * 8;
      async_load16(Kb + (size_t)(s0 + r0 + srow8) * kstride + scol, &Ks[r0 * 64]);
    }
    asm volatile("" ::: "memory");
    // V transpose store (compiler waits v0/v1 only; K(t) newer, stays in flight)
    union { uint4 u[2]; u16 e[16]; } vv; vv.u[0] = v0; vv.u[1] = v1;
    #pragma unroll
    for (int j = 0; j < 16; ++j) {
      int d = w * 16 + j;
      Vt[d * 64 + ((((lane >> 3) ^ (j & 7)) << 3) | (lane & 7))] = vv.e[j];
    }
    // prefetch next V
    if (s0 + 64 < nk) {
      v0 = *(const uint4*)&Vb[(size_t)(s0 + 64 + lane) * kstride + w * 16];
      v1 = *(const uint4*)&Vb[(size_t)(s0 + 64 + lane) * kstride + w * 16 + 8];
      asm volatile("s_waitcnt vmcnt(2)" ::: "memory");  // K(t) done; V(t+1) flying
    } else {
      asm volatile("s_waitcnt vmcnt(0)" ::: "memory");
    }
    asm volatile("s_waitcnt lgkmcnt(0)" ::: "memory");  // Vt committed
    __builtin_amdgcn_s_barrier();

    #pragma unroll
    for (int rb = 0; rb < 2; ++rb) {
      if (rb == 0 && causal && s0 >= qt + 64) continue;  // rb0 fully masked (uniform)
      int tg0 = qt + rb * 64 + w * 16 + quad * 4;

      // ---- QK^T ----
      f32x4 sacc[4];
      #pragma unroll
      for (int ni = 0; ni < 4; ++ni) sacc[ni] = (f32x4){0.f, 0.f, 0.f, 0.f};
      __builtin_amdgcn_s_setprio(1);
      #pragma unroll
      for (int c = 0; c < 2; ++c) {
        #pragma unroll
        for (int ni = 0; ni < 4; ++ni) {
          bf16x8 kf = *(const bf16x8*)&Ks[(ni * 16 + l15) * 64 + (((c * 4 + quad) ^ (l15 & 7)) << 3)];
          sacc[ni] = __builtin_amdgcn_mfma_f32_16x16x32_bf16(qfrag[rb][c], kf, sacc[ni], 0, 0, 0);
        }
      }
      __builtin_amdgcn_s_setprio(0);

      #pragma unroll
      for (int ni = 0; ni < 4; ++ni)
        #pragma unroll
        for (int r = 0; r < 4; ++r) sacc[ni][r] *= 0.125f;
      if (causal && s0 + 63 > qt + rb * 64 + w * 16) {  // diagonal tiles only (uniform per wave)
        #pragma unroll
        for (int ni = 0; ni < 4; ++ni) {
          int key = s0 + ni * 16 + l15;
          #pragma unroll
          for (int r = 0; r < 4; ++r)
            if (key > tg0 + r) sacc[ni][r] = -1e30f;
        }
      }

      // ---- online softmax ----
      float mnew[4], alpha[4], psum[4];
      #pragma unroll
      for (int r = 0; r < 4; ++r) {
        float mx = fmaxf(fmaxf(sacc[0][r], sacc[1][r]), fmaxf(sacc[2][r], sacc[3][r]));
        #pragma unroll
        for (int off = 1; off < 16; off <<= 1) mx = fmaxf(mx, __shfl_xor(mx, off));
        mnew[r] = fmaxf(m_i[rb][r], mx);
        alpha[r] = __expf(m_i[rb][r] - mnew[r]);
        m_i[rb][r] = mnew[r];
        psum[r] = 0.f;
      }
      #pragma unroll
      for (int ni = 0; ni < 4; ++ni) {
        #pragma unroll
        for (int r = 0; r < 4; ++r) {
          float p = __expf(sacc[ni][r] - mnew[r]);
          psum[r] += p;
          int row = quad * 4 + r;
          int blk = (ni * 2 + (l15 >> 3)) ^ (row & 7);
          Ps[(w * 32 + rb * 16 + row) * 64 + (blk << 3) + (l15 & 7)] = f2bf(p);
        }
      }
      #pragma unroll
      for (int r = 0; r < 4; ++r) {
        float ps = psum[r];
        #pragma unroll
        for (int off = 1; off < 16; off <<= 1) ps += __shfl_xor(ps, off);
        l_i[rb][r] = l_i[rb][r] * alpha[r] + ps;
      }

      // ---- PV ----
      bf16x8 pfrag[2];
      #pragma unroll
      for (int c = 0; c < 2; ++c)
        pfrag[c] = *(const bf16x8*)&Ps[(w * 32 + rb * 16 + l15) * 64 + (((c * 4 + quad) ^ (l15 & 7)) << 3)];
      #pragma unroll
      for (int ni = 0; ni < 4; ++ni)
        #pragma unroll
        for (int r = 0; r < 4; ++r) oacc[rb][ni][r] *= alpha[r];
      __builtin_amdgcn_s_setprio(1);
      #pragma unroll
      for (int c = 0; c < 2; ++c) {
        #pragma unroll
        for (int ni = 0; ni < 4; ++ni) {
          bf16x8 vf = *(const bf16x8*)&Vt[(ni * 16 + l15) * 64 + (((c * 4 + quad) ^ (l15 & 7)) << 3)];
          oacc[rb][ni] = __builtin_amdgcn_mfma_f32_16x16x32_bf16(pfrag[c], vf, oacc[rb][ni], 0, 0, 0);
        }
      }
      __builtin_amdgcn_s_setprio(0);
    }
  }

  #pragma unroll
  for (int rb = 0; rb < 2; ++rb) {
    int tg0 = qt + rb * 64 + w * 16 + quad * 4;
    #pragma unroll
    for (int ni = 0; ni < 4; ++ni) {
      #pragma unroll
      for (int r = 0; r < 4; ++r) {
        int t = tg0 + r;
        int d = ni * 16 + l15;
        Ob[(size_t)t * 1024 + d] = f2bf(oacc[rb][ni][r] / l_i[rb][r]);
      }
    }
  }
}

extern "C" void kernel_launch(void* const* d_in, const int* in_sizes, int n_in,
                              void* d_out, int out_size, void* d_ws, size_t ws_size,
                              hipStream_t stream) {
  const void* x_in   = d_in[0];
  const void* enc_in = d_in[1];
  const void* ln1_w = d_in[4];  const void* ln1_b = d_in[5];
  const void* qkv_w = d_in[6];  const void* qkv_b = d_in[7];
  const void* proj_w = d_in[8]; const void* proj_b = d_in[9];
  const void* ln2_w = d_in[10]; const void* ln2_b = d_in[11];
  const void* q_w = d_in[12];   const void* q_b = d_in[13];
  const void* k_w = d_in[14];   const void* k_b = d_in[15];
  const void* v_w = d_in[16];   const void* v_b = d_in[17];
  const void* out_w = d_in[18]; const void* out_b = d_in[19];
  const void* ln3_w = d_in[20]; const void* ln3_b = d_in[21];
  const void* mlp1_w = d_in[22]; const void* mlp1_b = d_in[23];
  const void* mlp2_w = d_in[24]; const void* mlp2_b = d_in[25];

  char* ws = (char*)d_ws;
  size_t off = 0;
  auto alloc = [&](size_t bytes) { char* p = ws + off; off += (bytes + 255) & ~(size_t)255; return p; };
  float* xf   = (float*)alloc(4096ull * 1024 * 4);
  u16* hb     = (u16*)alloc(4096ull * 1024 * 2);
  u16* big    = (u16*)alloc(4096ull * 4096 * 2);
  u16* wT     = (u16*)alloc(3072ull * 1024 * 2);
  u16* encb   = (u16*)alloc(2304ull * 768 * 2);
  u16* pool   = (u16*)alloc(20480ull * 2);
  int* flag   = (int*)alloc(256);
  (void)ws_size;

  u16* q_bf = big;
  u16* k_bf = big + 4096ull * 1024;
  u16* v_bf = big + (4096ull + 2304) * 1024;

  u16 *p_ln1w = pool, *p_ln1b = pool + 1024, *p_ln2w = pool + 2048, *p_ln2b = pool + 3072;
  u16 *p_ln3w = pool + 4096, *p_ln3b = pool + 5120;
  u16 *p_qkvb = pool + 6144, *p_projb = pool + 9216, *p_qb = pool + 10240, *p_kb = pool + 11264;
  u16 *p_vb = pool + 12288, *p_outb = pool + 13312, *p_m1b = pool + 14336, *p_m2b = pool + 18432;

  // ---- dtype sniff + input conversion ----
  sniff_kernel<<<1, 64, 0, stream>>>((const u16*)x_in, flag);
  in2f32_kernel<<<4096, 256, 0, stream>>>(x_in, xf, 1048576, flag);
  in2bf_kernel<<<1728, 256, 0, stream>>>(enc_in, encb, 442368, flag);
  small2bf_kernel<<<19, 256, 0, stream>>>(ln1_w, ln1_b, ln2_w, ln2_b, ln3_w, ln3_b,
                                          qkv_b, proj_b, q_b, k_b, v_b, out_b,
                                          mlp1_b, mlp2_b, pool, flag);

  // ---- self-attention block ----
  ln_kernel<<<4096, 256, 0, stream>>>(xf, p_ln1w, p_ln1b, hb);
  transpose_k<<<dim3(96, 32), 256, 0, stream>>>(qkv_w, wT, 1024, 3072, flag);
  gemm_tn<0, 128><<<dim3(24, 32), 256, 0, stream>>>(hb, wT, p_qkvb, nullptr, nullptr, big, 4096, 3072, 1024, flag);
  attn_mfma<<<dim3(8, 64), 256, 0, stream>>>(big, big + 1024, big + 2048, hb, 1024, 1024, 3072, 3072, 1);
  transpose_k<<<dim3(32, 32), 256, 0, stream>>>(proj_w, wT, 1024, 1024, flag);
  gemm_tn<1, 64><<<dim3(16, 32), 256, 0, stream>>>(hb, wT, p_projb, xf, xf, nullptr, 4096, 1024, 1024, flag);

  // ---- cross-attention block ----
  ln_kernel<<<4096, 256, 0, stream>>>(xf, p_ln2w, p_ln2b, hb);
  transpose_k<<<dim3(32, 32), 256, 0, stream>>>(q_w, wT, 1024, 1024, flag);
  gemm_tn<0, 64><<<dim3(16, 32), 256, 0, stream>>>(hb, wT, p_qb, nullptr, nullptr, q_bf, 4096, 1024, 1024, flag);
  transpose_k<<<dim3(32, 24), 256, 0, stream>>>(k_w, wT, 768, 1024, flag);
  gemm_tn<0, 64><<<dim3(16, 18), 256, 0, stream>>>(encb, wT, p_kb, nullptr, nullptr, k_bf, 2304, 1024, 768, flag);
  transpose_k<<<dim3(32, 24), 256, 0, stream>>>(v_w, wT, 768, 1024, flag);
  gemm_tn<0, 64><<<dim3(16, 18), 256, 0, stream>>>(encb, wT, p_vb, nullptr, nullptr, v_bf, 2304, 1024, 768, flag);
  attn_mfma<<<dim3(8, 64), 256, 0, stream>>>(q_bf, k_bf, v_bf, hb, 1024, 576, 1024, 1024, 0);
  transpose_k<<<dim3(32, 32), 256, 0, stream>>>(out_w, wT, 1024, 1024, flag);
  gemm_tn<1, 64><<<dim3(16, 32), 256, 0, stream>>>(hb, wT, p_outb, xf, xf, nullptr, 4096, 1024, 1024, flag);

  // ---- MLP block ----
  ln_kernel<<<4096, 256, 0, stream>>>(xf, p_ln3w, p_ln3b, hb);
  transpose_k<<<dim3(128, 32), 256, 0, stream>>>(mlp1_w, wT, 1024, 4096, flag);
  gemm_tn<2, 128><<<dim3(32, 32), 256, 0, stream>>>(hb, wT, p_m1b, nullptr, nullptr, big, 4096, 4096, 1024, flag);
  transpose_k<<<dim3(32, 128), 256, 0, stream>>>(mlp2_w, wT, 4096, 1024, flag);
  gemm_tn<3, 64><<<dim3(16, 32), 256, 0, stream>>>(big, wT, p_m2b, xf, nullptr, d_out, 4096, 1024, 4096, flag);
}

// Round 8
// 533.557 us; speedup vs baseline: 1.1276x; 1.0823x over previous
//
#include <hip/hip_runtime.h>
#include <hip/hip_bf16.h>

typedef unsigned short u16;
typedef __bf16 bf16x8 __attribute__((ext_vector_type(8)));
typedef float f32x4 __attribute__((ext_vector_type(4)));

__device__ __forceinline__ float bf2f(u16 v) { return __uint_as_float(((unsigned)v) << 16); }
__device__ __forceinline__ u16 f2bf(float f) {
  unsigned u = __float_as_uint(f);
  u += 0x7FFFu + ((u >> 16) & 1u);
  return (u16)(u >> 16);
}
__device__ __forceinline__ float gelu_exact(float x) {
  return 0.5f * x * (1.0f + erff(x * 0.70710678118654752f));
}

// async global->LDS DMA, 16B per lane; LDS dest = wave-uniform base + lane*16
__device__ __forceinline__ void async_load16(const u16* g, u16* l) {
  __builtin_amdgcn_global_load_lds((const __attribute__((address_space(1))) void*)g,
                                   (__attribute__((address_space(3))) void*)l, 16, 0, 0);
}

// ---------------- dtype sniffer (1 = bf16, 0 = fp32) ----------------
__global__ void sniff_kernel(const u16* __restrict__ x, int* __restrict__ flag) {
  int tid = threadIdx.x;  // 64
  int hits = 0;
  #pragma unroll
  for (int s = 0; s < 2; ++s) {
    float f = fabsf(bf2f(x[2 * (tid + 64 * s)]));
    hits += (f >= 0.00390625f && f <= 16.0f) ? 1 : 0;
  }
  #pragma unroll
  for (int off = 32; off; off >>= 1) hits += __shfl_xor(hits, off);
  if (tid == 0) flag[0] = (hits >= 64) ? 1 : 0;
}

// ---------------- input -> bf16 copy/convert ----------------
__global__ __launch_bounds__(256) void in2bf_kernel(const void* __restrict__ src, u16* __restrict__ dst,
                                                    int n4, const int* __restrict__ flagp) {
  int i = blockIdx.x * 256 + threadIdx.x;
  if (i >= n4) return;
  if (*flagp) {
    ((ushort4*)dst)[i] = ((const ushort4*)src)[i];
  } else {
    float4 v = ((const float4*)src)[i];
    ushort4 o; o.x = f2bf(v.x); o.y = f2bf(v.y); o.z = f2bf(v.z); o.w = f2bf(v.w);
    ((ushort4*)dst)[i] = o;
  }
}

// ---------------- all small params (LN w/b + biases) -> bf16 pool, ONE launch ----------------
__global__ __launch_bounds__(256) void small2bf_kernel(
    const void* s0, const void* s1, const void* s2, const void* s3,
    const void* s4, const void* s5, const void* s6, const void* s7,
    const void* s8, const void* s9, const void* s10, const void* s11,
    const void* s12, const void* s13,
    u16* __restrict__ dst, const int* __restrict__ flagp) {
  const void* srcs[14] = {s0, s1, s2, s3, s4, s5, s6, s7, s8, s9, s10, s11, s12, s13};
  int blk = blockIdx.x;
  int seg, u;
  if (blk < 6)       { seg = blk;            u = 0; }
  else if (blk < 9)  { seg = 6;              u = blk - 6; }
  else if (blk < 14) { seg = 7 + (blk - 9);  u = 0; }
  else if (blk < 18) { seg = 12;             u = blk - 14; }
  else               { seg = 13;             u = 0; }
  const void* src = srcs[seg];
  int i = threadIdx.x + u * 256;  // ushort4/float4 index within source
  u16* d = dst + (size_t)blk * 1024;
  if (*flagp) {
    ((ushort4*)d)[threadIdx.x] = ((const ushort4*)src)[i];
  } else {
    float4 v = ((const float4*)src)[i];
    ushort4 o; o.x = f2bf(v.x); o.y = f2bf(v.y); o.z = f2bf(v.z); o.w = f2bf(v.w);
    ((ushort4*)d)[threadIdx.x] = o;
  }
}

// ---------------- input -> fp32 copy/convert (residual stream init) ----------------
__global__ __launch_bounds__(256) void in2f32_kernel(const void* __restrict__ src, float* __restrict__ dst,
                                                     int n4, const int* __restrict__ flagp) {
  int i = blockIdx.x * 256 + threadIdx.x;
  if (i >= n4) return;
  if (*flagp) {
    ushort4 v = ((const ushort4*)src)[i];
    float4 o; o.x = bf2f(v.x); o.y = bf2f(v.y); o.z = bf2f(v.z); o.w = bf2f(v.w);
    ((float4*)dst)[i] = o;
  } else {
    ((float4*)dst)[i] = ((const float4*)src)[i];
  }
}

// ---------------- weight transpose: in [R,C] -> out [C,R] bf16, dual-dtype read ----------------
__global__ __launch_bounds__(256) void transpose_k(const void* __restrict__ in_, u16* __restrict__ out,
                                                   int R, int C, const int* __restrict__ flagp) {
  int flag = *flagp;
  __shared__ u16 tile[32][33];
  int c0 = blockIdx.x * 32, r0 = blockIdx.y * 32;
  int tx = threadIdx.x & 31, ty = threadIdx.x >> 5;
  #pragma unroll
  for (int j = 0; j < 32; j += 8) {
    size_t idx = (size_t)(r0 + ty + j) * C + c0 + tx;
    tile[ty + j][tx] = flag ? ((const u16*)in_)[idx] : f2bf(((const float*)in_)[idx]);
  }
  __syncthreads();
  #pragma unroll
  for (int j = 0; j < 32; j += 8)
    out[(size_t)(c0 + ty + j) * R + r0 + tx] = tile[tx][ty + j];
}

// ---------------- LayerNorm: fp32 in -> bf16 out, D=1024 ----------------
__global__ __launch_bounds__(256) void ln_kernel(const float* __restrict__ x,
                                                 const u16* __restrict__ w, const u16* __restrict__ b,
                                                 u16* __restrict__ out) {
  int row = blockIdx.x, tid = threadIdx.x;
  float4 v = ((const float4*)(x + (size_t)row * 1024))[tid];
  float s = v.x + v.y + v.z + v.w;
  #pragma unroll
  for (int off = 32; off; off >>= 1) s += __shfl_xor(s, off);
  __shared__ float red1[4], red2[4];
  if ((tid & 63) == 0) red1[tid >> 6] = s;
  __syncthreads();
  float mean = (red1[0] + red1[1] + red1[2] + red1[3]) * (1.0f / 1024.0f);
  float d0 = v.x - mean, d1 = v.y - mean, d2 = v.z - mean, d3 = v.w - mean;
  float vs = d0 * d0 + d1 * d1 + d2 * d2 + d3 * d3;
  #pragma unroll
  for (int off = 32; off; off >>= 1) vs += __shfl_xor(vs, off);
  if ((tid & 63) == 0) red2[tid >> 6] = vs;
  __syncthreads();
  float var = (red2[0] + red2[1] + red2[2] + red2[3]) * (1.0f / 1024.0f);
  float rs = rsqrtf(var + 1e-5f);
  int c = tid * 4;
  ushort4 o;
  o.x = f2bf(d0 * rs * bf2f(w[c + 0]) + bf2f(b[c + 0]));
  o.y = f2bf(d1 * rs * bf2f(w[c + 1]) + bf2f(b[c + 1]));
  o.z = f2bf(d2 * rs * bf2f(w[c + 2]) + bf2f(b[c + 2]));
  o.w = f2bf(d3 * rs * bf2f(w[c + 3]) + bf2f(b[c + 3]));
  ((ushort4*)(out + (size_t)row * 1024))[tid] = o;
}

// ---------------- TN GEMM: C[M,N] = A[M,K] @ Bt[N,K]^T + bias, bf16 MFMA ----------------
// 4-wave 128xTN tile (round-3 proven) — used for skinny-N shapes.
template <int MODE, int TN>
__global__ __launch_bounds__(256) void gemm_tn(const u16* __restrict__ A, const u16* __restrict__ Bt,
                                               const u16* __restrict__ bias,
                                               const float* __restrict__ resid_in, float* __restrict__ resid_out,
                                               void* __restrict__ outp, int M, int N, int K,
                                               const int* __restrict__ flagp) {
  constexpr int NI = TN / 32;
  __shared__ __align__(16) u16 As[128 * 64];
  __shared__ __align__(16) u16 Bs[TN * 64];

  int nwg = gridDim.x * gridDim.y;
  int bid = blockIdx.y * gridDim.x + blockIdx.x;
  int chunk = nwg >> 3;
  int s = (bid & 7) * chunk + (bid >> 3);
  int bx = s % gridDim.x, by = s / gridDim.x;

  int n0 = bx * TN, m0 = by * 128;
  int tid = threadIdx.x;
  int lane = tid & 63, w = tid >> 6;
  int wm = w & 1, wn = w >> 1;
  int quad = lane >> 4, l15 = lane & 15;
  int sw = l15 & 7;
  int flag = (MODE == 3) ? *flagp : 0;
  f32x4 acc[4][NI];
  #pragma unroll
  for (int i = 0; i < 4; i++)
    #pragma unroll
    for (int j = 0; j < NI; j++) acc[i][j] = (f32x4){0.f, 0.f, 0.f, 0.f};

  int srow8 = lane >> 3;
  int scol = ((lane & 7) ^ srow8) * 8;
  const u16* Abase = A + (size_t)(m0 + srow8) * K + scol;
  const u16* Bbase = Bt + (size_t)(n0 + srow8) * K + scol;

  for (int k0 = 0; k0 < K; k0 += 64) {
    #pragma unroll
    for (int j = 0; j < 4; ++j) {
      int r0 = (w * 4 + j) * 8;
      async_load16(Abase + (size_t)r0 * K + k0, &As[r0 * 64]);
    }
    #pragma unroll
    for (int j = 0; j < TN / 32; ++j) {
      int r0 = (w * (TN / 32) + j) * 8;
      async_load16(Bbase + (size_t)r0 * K + k0, &Bs[r0 * 64]);
    }
    __syncthreads();
    #pragma unroll
    for (int kk = 0; kk < 64; kk += 32) {
      int cbase = (kk >> 3) + quad;
      int slot = (cbase ^ sw) << 3;
      bf16x8 af[4], bfr[NI];
      #pragma unroll
      for (int i = 0; i < 4; i++)
        af[i] = *(const bf16x8*)&As[(wm * 64 + i * 16 + l15) * 64 + slot];
      #pragma unroll
      for (int j = 0; j < NI; j++)
        bfr[j] = *(const bf16x8*)&Bs[(wn * (TN / 2) + j * 16 + l15) * 64 + slot];
      #pragma unroll
      for (int mi = 0; mi < 4; mi++)
        #pragma unroll
        for (int ni = 0; ni < NI; ni++)
          acc[mi][ni] = __builtin_amdgcn_mfma_f32_16x16x32_bf16(af[mi], bfr[ni], acc[mi][ni], 0, 0, 0);
    }
    __syncthreads();
  }

  int col_base = n0 + wn * (TN / 2), row_base = m0 + wm * 64;
  #pragma unroll
  for (int mi = 0; mi < 4; mi++) {
    #pragma unroll
    for (int ni = 0; ni < NI; ni++) {
      int col = col_base + ni * 16 + l15;
      float bv = bf2f(bias[col]);
      #pragma unroll
      for (int r = 0; r < 4; r++) {
        int row = row_base + mi * 16 + quad * 4 + r;
        float vv = acc[mi][ni][r] + bv;
        size_t idx = (size_t)row * N + col;
        if (MODE == 0) ((u16*)outp)[idx] = f2bf(vv);
        else if (MODE == 1) resid_out[idx] = resid_in[idx] + vv;
        else if (MODE == 2) ((u16*)outp)[idx] = f2bf(gelu_exact(vv));
        else {
          float ov = resid_in[idx] + vv;
          if (flag) ((u16*)outp)[idx] = f2bf(ov);
          else ((float*)outp)[idx] = ov;
        }
      }
    }
  }
}

// ---------------- WIDE TN GEMM: 256x128 tile, 8 waves (512 thr) ----------------
// For the fat-N K=1024 gemms (qkv N=3072, mlp1 N=4096). Round-6 profile: mlp1
// staged 537 MB at ~5.0 TB/s delivered = 107 us -> staging-throughput-bound.
// 256x128 tile cuts staged bytes 27% (mlp1 537->393 MB, qkv 402->302 MB) while
// keeping the EXACT per-wave inner loop (4x4 acc, same XOR swizzle, same NB=1
// two-barrier K-step). 8 waves = 4(m) x 2(n); LDS 48 KB -> 2 blocks/CU.
template <int MODE>
__global__ __launch_bounds__(512) void gemm_wide(const u16* __restrict__ A, const u16* __restrict__ Bt,
                                                 const u16* __restrict__ bias,
                                                 void* __restrict__ outp, int M, int N, int K) {
  __shared__ __align__(16) u16 As[256 * 64];
  __shared__ __align__(16) u16 Bs[128 * 64];

  int nwg = gridDim.x * gridDim.y;
  int bid = blockIdx.y * gridDim.x + blockIdx.x;
  int chunk = nwg >> 3;
  int s = (bid & 7) * chunk + (bid >> 3);
  int bx = s % gridDim.x, by = s / gridDim.x;

  int n0 = bx * 128, m0 = by * 256;
  int tid = threadIdx.x;
  int lane = tid & 63, w = tid >> 6;     // w in 0..7
  int wm = w & 3, wn = w >> 2;           // 4 (m) x 2 (n) waves; per-wave out 64x64
  int quad = lane >> 4, l15 = lane & 15;
  int sw = l15 & 7;
  f32x4 acc[4][4];
  #pragma unroll
  for (int i = 0; i < 4; i++)
    #pragma unroll
    for (int j = 0; j < 4; j++) acc[i][j] = (f32x4){0.f, 0.f, 0.f, 0.f};

  int srow8 = lane >> 3;
  int scol = ((lane & 7) ^ srow8) * 8;
  const u16* Abase = A + (size_t)(m0 + srow8) * K + scol;
  const u16* Bbase = Bt + (size_t)(n0 + srow8) * K + scol;

  for (int k0 = 0; k0 < K; k0 += 64) {
    #pragma unroll
    for (int j = 0; j < 4; ++j) {                  // A: 256 rows = 32 groups / 8 waves
      int r0 = (w * 4 + j) * 8;
      async_load16(Abase + (size_t)r0 * K + k0, &As[r0 * 64]);
    }
    #pragma unroll
    for (int j = 0; j < 2; ++j) {                  // B: 128 rows = 16 groups / 8 waves
      int r0 = (w * 2 + j) * 8;
      async_load16(Bbase + (size_t)r0 * K + k0, &Bs[r0 * 64]);
    }
    __syncthreads();
    #pragma unroll
    for (int kk = 0; kk < 64; kk += 32) {
      int cbase = (kk >> 3) + quad;
      int slot = (cbase ^ sw) << 3;
      bf16x8 af[4], bfr[4];
      #pragma unroll
      for (int i = 0; i < 4; i++)
        af[i] = *(const bf16x8*)&As[(wm * 64 + i * 16 + l15) * 64 + slot];
      #pragma unroll
      for (int j = 0; j < 4; j++)
        bfr[j] = *(const bf16x8*)&Bs[(wn * 64 + j * 16 + l15) * 64 + slot];
      #pragma unroll
      for (int mi = 0; mi < 4; mi++)
        #pragma unroll
        for (int ni = 0; ni < 4; ni++)
          acc[mi][ni] = __builtin_amdgcn_mfma_f32_16x16x32_bf16(af[mi], bfr[ni], acc[mi][ni], 0, 0, 0);
    }
    __syncthreads();
  }

  int col_base = n0 + wn * 64, row_base = m0 + wm * 64;
  #pragma unroll
  for (int mi = 0; mi < 4; mi++) {
    #pragma unroll
    for (int ni = 0; ni < 4; ni++) {
      int col = col_base + ni * 16 + l15;
      float bv = bf2f(bias[col]);
      #pragma unroll
      for (int r = 0; r < 4; r++) {
        int row = row_base + mi * 16 + quad * 4 + r;
        float vv = acc[mi][ni][r] + bv;
        size_t idx = (size_t)row * N + col;
        if (MODE == 0) ((u16*)outp)[idx] = f2bf(vv);
        else ((u16*)outp)[idx] = f2bf(gelu_exact(vv));
      }
    }
  }
}

// ---------------- MFMA flash attention, HD=64, QBLK=64 (round-4 numerics-proven) ----------------
// Reverted from QBLK=128: that variant shifted absmax 0.031->0.102 (codegen-
// sensitive rounding), leaving no threshold margin. This version measured
// absmax 0.03125 across 3 runs. Only change vs round 4: scheduling-only slot
// remap -- all 16 q-tiles of a head issue consecutively on ONE XCD (slot&7),
// so the head's K/V stays XCD-L2-resident; causal depths interleave per XCD.
// Zero numeric impact (bijective (bh,qi) remap; per-pair math identical).
__global__ __launch_bounds__(256) void attn_mfma(const u16* __restrict__ Q, const u16* __restrict__ K,
                                                 const u16* __restrict__ V, u16* __restrict__ O,
                                                 int T, int S, int qstride, int kstride, int causal) {
  int slot = blockIdx.y * gridDim.x + blockIdx.x;  // grid (16,64) -> 0..1023
  int c = slot & 7, u = slot >> 3;
  int bh = c * 8 + (u >> 4);      // 8 heads per XCD, consecutive slots same head
  int qi = u & 15;                // all 16 q-tiles of the head back-to-back
  int b = bh >> 4, h = bh & 15;
  int qt = qi * 64;

  const u16* Qb = Q + (size_t)b * T * qstride + h * 64;
  const u16* Kb = K + (size_t)b * S * kstride + h * 64;
  const u16* Vb = V + (size_t)b * S * kstride + h * 64;
  u16* Ob = O + (size_t)b * T * 1024 + h * 64;

  int tid = threadIdx.x, lane = tid & 63, w = tid >> 6;
  int quad = lane >> 4, l15 = lane & 15;

  __shared__ __align__(16) u16 Ks[64 * 64];
  __shared__ __align__(16) u16 Vt[64 * 64];
  __shared__ __align__(16) u16 Ps[4][16 * 64];

  int srow8 = lane >> 3;
  int scol = ((lane & 7) ^ srow8) * 8;

  // ---- stage Q via DMA (into Ks), prefetch V(0) regs ----
  #pragma unroll
  for (int j = 0; j < 2; ++j) {
    int r0 = (w * 2 + j) * 8;
    async_load16(Qb + (size_t)(qt + r0 + srow8) * qstride + scol, &Ks[r0 * 64]);
  }
  asm volatile("" ::: "memory");
  uint4 v0 = *(const uint4*)&Vb[(size_t)lane * kstride + w * 16];
  uint4 v1 = *(const uint4*)&Vb[(size_t)lane * kstride + w * 16 + 8];
  asm volatile("s_waitcnt vmcnt(2)" ::: "memory");  // Q DMA done; V(0) in flight
  __builtin_amdgcn_s_barrier();

  int qrow = w * 16 + l15;
  bf16x8 qfrag[2];
  #pragma unroll
  for (int cc = 0; cc < 2; ++cc)
    qfrag[cc] = *(const bf16x8*)&Ks[qrow * 64 + (((cc * 4 + quad) ^ (l15 & 7)) << 3)];
  asm volatile("s_waitcnt lgkmcnt(0)" ::: "memory");  // qfrag reads retired before Ks overwrite

  float m_i[4], l_i[4];
  f32x4 oacc[4];
  #pragma unroll
  for (int r = 0; r < 4; ++r) { m_i[r] = -1e30f; l_i[r] = 0.f; }
  #pragma unroll
  for (int ni = 0; ni < 4; ++ni) oacc[ni] = (f32x4){0.f, 0.f, 0.f, 0.f};

  int nk = causal ? (qi + 1) * 64 : S;
  int tg0 = qt + w * 16 + quad * 4;

  for (int s0 = 0; s0 < nk; s0 += 64) {
    __builtin_amdgcn_s_barrier();  // prev tile fully consumed by all waves
    // K DMA for this tile
    #pragma unroll
    for (int j = 0; j < 2; ++j) {
      int r0 = (w * 2 + j) * 8;
      async_load16(Kb + (size_t)(s0 + r0 + srow8) * kstride + scol, &Ks[r0 * 64]);
    }
    asm volatile("" ::: "memory");
    // V transpose store: row d uniform per store, col = lane (conflict-free)
    union { uint4 u4[2]; u16 e[16]; } vv; vv.u4[0] = v0; vv.u4[1] = v1;
    #pragma unroll
    for (int j = 0; j < 16; ++j) {
      int d = w * 16 + j;
      Vt[d * 64 + ((((lane >> 3) ^ (j & 7)) << 3) | (lane & 7))] = vv.e[j];
    }
    // prefetch next V
    if (s0 + 64 < nk) {
      v0 = *(const uint4*)&Vb[(size_t)(s0 + 64 + lane) * kstride + w * 16];
      v1 = *(const uint4*)&Vb[(size_t)(s0 + 64 + lane) * kstride + w * 16 + 8];
      asm volatile("s_waitcnt vmcnt(2)" ::: "memory");  // K DMA done; V(t+1) flying
    } else {
      asm volatile("s_waitcnt vmcnt(0)" ::: "memory");
    }
    asm volatile("s_waitcnt lgkmcnt(0)" ::: "memory");  // Vt stores committed
    __builtin_amdgcn_s_barrier();

    // ---- QK^T ----
    f32x4 sacc[4];
    #pragma unroll
    for (int ni = 0; ni < 4; ++ni) sacc[ni] = (f32x4){0.f, 0.f, 0.f, 0.f};
    __builtin_amdgcn_s_setprio(1);
    #pragma unroll
    for (int cc = 0; cc < 2; ++cc) {
      #pragma unroll
      for (int ni = 0; ni < 4; ++ni) {
        bf16x8 kf = *(const bf16x8*)&Ks[(ni * 16 + l15) * 64 + (((cc * 4 + quad) ^ (l15 & 7)) << 3)];
        sacc[ni] = __builtin_amdgcn_mfma_f32_16x16x32_bf16(qfrag[cc], kf, sacc[ni], 0, 0, 0);
      }
    }
    __builtin_amdgcn_s_setprio(0);

    #pragma unroll
    for (int ni = 0; ni < 4; ++ni)
      #pragma unroll
      for (int r = 0; r < 4; ++r) sacc[ni][r] *= 0.125f;
    if (causal && s0 + 63 > qt + w * 16) {  // wave-uniform: only diagonal tile
      #pragma unroll
      for (int ni = 0; ni < 4; ++ni) {
        int key = s0 + ni * 16 + l15;
        #pragma unroll
        for (int r = 0; r < 4; ++r)
          if (key > tg0 + r) sacc[ni][r] = -1e30f;
      }
    }

    // ---- online softmax ----
    float mnew[4], alpha[4], psum[4];
    #pragma unroll
    for (int r = 0; r < 4; ++r) {
      float mx = fmaxf(fmaxf(sacc[0][r], sacc[1][r]), fmaxf(sacc[2][r], sacc[3][r]));
      #pragma unroll
      for (int off = 1; off < 16; off <<= 1) mx = fmaxf(mx, __shfl_xor(mx, off));
      mnew[r] = fmaxf(m_i[r], mx);
      alpha[r] = __expf(m_i[r] - mnew[r]);
      m_i[r] = mnew[r];
      psum[r] = 0.f;
    }
    #pragma unroll
    for (int ni = 0; ni < 4; ++ni) {
      #pragma unroll
      for (int r = 0; r < 4; ++r) {
        float p = __expf(sacc[ni][r] - mnew[r]);
        psum[r] += p;
        int row = quad * 4 + r;
        int blk = (ni * 2 + (l15 >> 3)) ^ (row & 7);
        Ps[w][row * 64 + (blk << 3) + (l15 & 7)] = f2bf(p);
      }
    }
    #pragma unroll
    for (int r = 0; r < 4; ++r) {
      float ps = psum[r];
      #pragma unroll
      for (int off = 1; off < 16; off <<= 1) ps += __shfl_xor(ps, off);
      l_i[r] = l_i[r] * alpha[r] + ps;
    }

    // ---- PV ----
    bf16x8 pfrag[2];
    #pragma unroll
    for (int cc = 0; cc < 2; ++cc)
      pfrag[cc] = *(const bf16x8*)&Ps[w][l15 * 64 + (((cc * 4 + quad) ^ (l15 & 7)) << 3)];
    #pragma unroll
    for (int ni = 0; ni < 4; ++ni)
      #pragma unroll
      for (int r = 0; r < 4; ++r) oacc[ni][r] *= alpha[r];
    __builtin_amdgcn_s_setprio(1);
    #pragma unroll
    for (int cc = 0; cc < 2; ++cc) {
      #pragma unroll
      for (int ni = 0; ni < 4; ++ni) {
        bf16x8 vf = *(const bf16x8*)&Vt[(ni * 16 + l15) * 64 + (((cc * 4 + quad) ^ (l15 & 7)) << 3)];
        oacc[ni] = __builtin_amdgcn_mfma_f32_16x16x32_bf16(pfrag[cc], vf, oacc[ni], 0, 0, 0);
      }
    }
    __builtin_amdgcn_s_setprio(0);
  }

  #pragma unroll
  for (int ni = 0; ni < 4; ++ni) {
    #pragma unroll
    for (int r = 0; r < 4; ++r) {
      int t = tg0 + r;
      int d = ni * 16 + l15;
      Ob[(size_t)t * 1024 + d] = f2bf(oacc[ni][r] / l_i[r]);
    }
  }
}

extern "C" void kernel_launch(void* const* d_in, const int* in_sizes, int n_in,
                              void* d_out, int out_size, void* d_ws, size_t ws_size,
                              hipStream_t stream) {
  const void* x_in   = d_in[0];
  const void* enc_in = d_in[1];
  const void* ln1_w = d_in[4];  const void* ln1_b = d_in[5];
  const void* qkv_w = d_in[6];  const void* qkv_b = d_in[7];
  const void* proj_w = d_in[8]; const void* proj_b = d_in[9];
  const void* ln2_w = d_in[10]; const void* ln2_b = d_in[11];
  const void* q_w = d_in[12];   const void* q_b = d_in[13];
  const void* k_w = d_in[14];   const void* k_b = d_in[15];
  const void* v_w = d_in[16];   const void* v_b = d_in[17];
  const void* out_w = d_in[18]; const void* out_b = d_in[19];
  const void* ln3_w = d_in[20]; const void* ln3_b = d_in[21];
  const void* mlp1_w = d_in[22]; const void* mlp1_b = d_in[23];
  const void* mlp2_w = d_in[24]; const void* mlp2_b = d_in[25];

  char* ws = (char*)d_ws;
  size_t off = 0;
  auto alloc = [&](size_t bytes) { char* p = ws + off; off += (bytes + 255) & ~(size_t)255; return p; };
  float* xf   = (float*)alloc(4096ull * 1024 * 4);
  u16* hb     = (u16*)alloc(4096ull * 1024 * 2);
  u16* big    = (u16*)alloc(4096ull * 4096 * 2);
  u16* wT     = (u16*)alloc(3072ull * 1024 * 2);
  u16* encb   = (u16*)alloc(2304ull * 768 * 2);
  u16* pool   = (u16*)alloc(20480ull * 2);
  int* flag   = (int*)alloc(256);
  (void)ws_size;

  u16* q_bf = big;
  u16* k_bf = big + 4096ull * 1024;
  u16* v_bf = big + (4096ull + 2304) * 1024;

  u16 *p_ln1w = pool, *p_ln1b = pool + 1024, *p_ln2w = pool + 2048, *p_ln2b = pool + 3072;
  u16 *p_ln3w = pool + 4096, *p_ln3b = pool + 5120;
  u16 *p_qkvb = pool + 6144, *p_projb = pool + 9216, *p_qb = pool + 10240, *p_kb = pool + 11264;
  u16 *p_vb = pool + 12288, *p_outb = pool + 13312, *p_m1b = pool + 14336, *p_m2b = pool + 18432;

  // ---- dtype sniff + input conversion ----
  sniff_kernel<<<1, 64, 0, stream>>>((const u16*)x_in, flag);
  in2f32_kernel<<<4096, 256, 0, stream>>>(x_in, xf, 1048576, flag);
  in2bf_kernel<<<1728, 256, 0, stream>>>(enc_in, encb, 442368, flag);
  small2bf_kernel<<<19, 256, 0, stream>>>(ln1_w, ln1_b, ln2_w, ln2_b, ln3_w, ln3_b,
                                          qkv_b, proj_b, q_b, k_b, v_b, out_b,
                                          mlp1_b, mlp2_b, pool, flag);

  // ---- self-attention block ----
  ln_kernel<<<4096, 256, 0, stream>>>(xf, p_ln1w, p_ln1b, hb);
  transpose_k<<<dim3(96, 32), 256, 0, stream>>>(qkv_w, wT, 1024, 3072, flag);
  gemm_wide<0><<<dim3(24, 16), 512, 0, stream>>>(hb, wT, p_qkvb, big, 4096, 3072, 1024);
  attn_mfma<<<dim3(16, 64), 256, 0, stream>>>(big, big + 1024, big + 2048, hb, 1024, 1024, 3072, 3072, 1);
  transpose_k<<<dim3(32, 32), 256, 0, stream>>>(proj_w, wT, 1024, 1024, flag);
  gemm_tn<1, 64><<<dim3(16, 32), 256, 0, stream>>>(hb, wT, p_projb, xf, xf, nullptr, 4096, 1024, 1024, flag);

  // ---- cross-attention block ----
  ln_kernel<<<4096, 256, 0, stream>>>(xf, p_ln2w, p_ln2b, hb);
  transpose_k<<<dim3(32, 32), 256, 0, stream>>>(q_w, wT, 1024, 1024, flag);
  gemm_tn<0, 64><<<dim3(16, 32), 256, 0, stream>>>(hb, wT, p_qb, nullptr, nullptr, q_bf, 4096, 1024, 1024, flag);
  transpose_k<<<dim3(32, 24), 256, 0, stream>>>(k_w, wT, 768, 1024, flag);
  gemm_tn<0, 64><<<dim3(16, 18), 256, 0, stream>>>(encb, wT, p_kb, nullptr, nullptr, k_bf, 2304, 1024, 768, flag);
  transpose_k<<<dim3(32, 24), 256, 0, stream>>>(v_w, wT, 768, 1024, flag);
  gemm_tn<0, 64><<<dim3(16, 18), 256, 0, stream>>>(encb, wT, p_vb, nullptr, nullptr, v_bf, 2304, 1024, 768, flag);
  attn_mfma<<<dim3(16, 64), 256, 0, stream>>>(q_bf, k_bf, v_bf, hb, 1024, 576, 1024, 1024, 0);
  transpose_k<<<dim3(32, 32), 256, 0, stream>>>(out_w, wT, 1024, 1024, flag);
  gemm_tn<1, 64><<<dim3(16, 32), 256, 0, stream>>>(hb, wT, p_outb, xf, xf, nullptr, 4096, 1024, 1024, flag);

  // ---- MLP block ----
  ln_kernel<<<4096, 256, 0, stream>>>(xf, p_ln3w, p_ln3b, hb);
  transpose_k<<<dim3(128, 32), 256, 0, stream>>>(mlp1_w, wT, 1024, 4096, flag);
  gemm_wide<2><<<dim3(32, 16), 512, 0, stream>>>(hb, wT, p_m1b, big, 4096, 4096, 1024);
  transpose_k<<<dim3(32, 128), 256, 0, stream>>>(mlp2_w, wT, 4096, 1024, flag);
  gemm_tn<3, 64><<<dim3(16, 32), 256, 0, stream>>>(big, wT, p_m2b, xf, nullptr, d_out, 4096, 1024, 4096, flag);
}

// Round 9
// 526.440 us; speedup vs baseline: 1.1428x; 1.0135x over previous
//
#include <hip/hip_runtime.h>
#include <hip/hip_bf16.h>

typedef unsigned short u16;
typedef __bf16 bf16x8 __attribute__((ext_vector_type(8)));
typedef float f32x4 __attribute__((ext_vector_type(4)));

__device__ __forceinline__ float bf2f(u16 v) { return __uint_as_float(((unsigned)v) << 16); }
__device__ __forceinline__ u16 f2bf(float f) {
  unsigned u = __float_as_uint(f);
  u += 0x7FFFu + ((u >> 16) & 1u);
  return (u16)(u >> 16);
}
__device__ __forceinline__ float gelu_exact(float x) {
  return 0.5f * x * (1.0f + erff(x * 0.70710678118654752f));
}

// async global->LDS DMA, 16B per lane; LDS dest = wave-uniform base + lane*16
__device__ __forceinline__ void async_load16(const u16* g, u16* l) {
  __builtin_amdgcn_global_load_lds((const __attribute__((address_space(1))) void*)g,
                                   (__attribute__((address_space(3))) void*)l, 16, 0, 0);
}

// ---------------- dtype sniffer (1 = bf16, 0 = fp32) ----------------
__global__ void sniff_kernel(const u16* __restrict__ x, int* __restrict__ flag) {
  int tid = threadIdx.x;  // 64
  int hits = 0;
  #pragma unroll
  for (int s = 0; s < 2; ++s) {
    float f = fabsf(bf2f(x[2 * (tid + 64 * s)]));
    hits += (f >= 0.00390625f && f <= 16.0f) ? 1 : 0;
  }
  #pragma unroll
  for (int off = 32; off; off >>= 1) hits += __shfl_xor(hits, off);
  if (tid == 0) flag[0] = (hits >= 64) ? 1 : 0;
}

// ---------------- input -> bf16 copy/convert ----------------
__global__ __launch_bounds__(256) void in2bf_kernel(const void* __restrict__ src, u16* __restrict__ dst,
                                                    int n4, const int* __restrict__ flagp) {
  int i = blockIdx.x * 256 + threadIdx.x;
  if (i >= n4) return;
  if (*flagp) {
    ((ushort4*)dst)[i] = ((const ushort4*)src)[i];
  } else {
    float4 v = ((const float4*)src)[i];
    ushort4 o; o.x = f2bf(v.x); o.y = f2bf(v.y); o.z = f2bf(v.z); o.w = f2bf(v.w);
    ((ushort4*)dst)[i] = o;
  }
}

// ---------------- all small params (LN w/b + biases) -> bf16 pool, ONE launch ----------------
__global__ __launch_bounds__(256) void small2bf_kernel(
    const void* s0, const void* s1, const void* s2, const void* s3,
    const void* s4, const void* s5, const void* s6, const void* s7,
    const void* s8, const void* s9, const void* s10, const void* s11,
    const void* s12, const void* s13,
    u16* __restrict__ dst, const int* __restrict__ flagp) {
  const void* srcs[14] = {s0, s1, s2, s3, s4, s5, s6, s7, s8, s9, s10, s11, s12, s13};
  int blk = blockIdx.x;
  int seg, u;
  if (blk < 6)       { seg = blk;            u = 0; }
  else if (blk < 9)  { seg = 6;              u = blk - 6; }
  else if (blk < 14) { seg = 7 + (blk - 9);  u = 0; }
  else if (blk < 18) { seg = 12;             u = blk - 14; }
  else               { seg = 13;             u = 0; }
  const void* src = srcs[seg];
  int i = threadIdx.x + u * 256;  // ushort4/float4 index within source
  u16* d = dst + (size_t)blk * 1024;
  if (*flagp) {
    ((ushort4*)d)[threadIdx.x] = ((const ushort4*)src)[i];
  } else {
    float4 v = ((const float4*)src)[i];
    ushort4 o; o.x = f2bf(v.x); o.y = f2bf(v.y); o.z = f2bf(v.z); o.w = f2bf(v.w);
    ((ushort4*)d)[threadIdx.x] = o;
  }
}

// ---------------- input -> fp32 copy/convert (residual stream init) ----------------
__global__ __launch_bounds__(256) void in2f32_kernel(const void* __restrict__ src, float* __restrict__ dst,
                                                     int n4, const int* __restrict__ flagp) {
  int i = blockIdx.x * 256 + threadIdx.x;
  if (i >= n4) return;
  if (*flagp) {
    ushort4 v = ((const ushort4*)src)[i];
    float4 o; o.x = bf2f(v.x); o.y = bf2f(v.y); o.z = bf2f(v.z); o.w = bf2f(v.w);
    ((float4*)dst)[i] = o;
  } else {
    ((float4*)dst)[i] = ((const float4*)src)[i];
  }
}

// ---------------- weight transpose: in [R,C] -> out [C,R] bf16, dual-dtype read ----------------
__global__ __launch_bounds__(256) void transpose_k(const void* __restrict__ in_, u16* __restrict__ out,
                                                   int R, int C, const int* __restrict__ flagp) {
  int flag = *flagp;
  __shared__ u16 tile[32][33];
  int c0 = blockIdx.x * 32, r0 = blockIdx.y * 32;
  int tx = threadIdx.x & 31, ty = threadIdx.x >> 5;
  #pragma unroll
  for (int j = 0; j < 32; j += 8) {
    size_t idx = (size_t)(r0 + ty + j) * C + c0 + tx;
    tile[ty + j][tx] = flag ? ((const u16*)in_)[idx] : f2bf(((const float*)in_)[idx]);
  }
  __syncthreads();
  #pragma unroll
  for (int j = 0; j < 32; j += 8)
    out[(size_t)(c0 + ty + j) * R + r0 + tx] = tile[tx][ty + j];
}

// ---------------- LayerNorm: fp32 in -> bf16 out, D=1024 ----------------
__global__ __launch_bounds__(256) void ln_kernel(const float* __restrict__ x,
                                                 const u16* __restrict__ w, const u16* __restrict__ b,
                                                 u16* __restrict__ out) {
  int row = blockIdx.x, tid = threadIdx.x;
  float4 v = ((const float4*)(x + (size_t)row * 1024))[tid];
  float s = v.x + v.y + v.z + v.w;
  #pragma unroll
  for (int off = 32; off; off >>= 1) s += __shfl_xor(s, off);
  __shared__ float red1[4], red2[4];
  if ((tid & 63) == 0) red1[tid >> 6] = s;
  __syncthreads();
  float mean = (red1[0] + red1[1] + red1[2] + red1[3]) * (1.0f / 1024.0f);
  float d0 = v.x - mean, d1 = v.y - mean, d2 = v.z - mean, d3 = v.w - mean;
  float vs = d0 * d0 + d1 * d1 + d2 * d2 + d3 * d3;
  #pragma unroll
  for (int off = 32; off; off >>= 1) vs += __shfl_xor(vs, off);
  if ((tid & 63) == 0) red2[tid >> 6] = vs;
  __syncthreads();
  float var = (red2[0] + red2[1] + red2[2] + red2[3]) * (1.0f / 1024.0f);
  float rs = rsqrtf(var + 1e-5f);
  int c = tid * 4;
  ushort4 o;
  o.x = f2bf(d0 * rs * bf2f(w[c + 0]) + bf2f(b[c + 0]));
  o.y = f2bf(d1 * rs * bf2f(w[c + 1]) + bf2f(b[c + 1]));
  o.z = f2bf(d2 * rs * bf2f(w[c + 2]) + bf2f(b[c + 2]));
  o.w = f2bf(d3 * rs * bf2f(w[c + 3]) + bf2f(b[c + 3]));
  ((ushort4*)(out + (size_t)row * 1024))[tid] = o;
}

// ---------------- TN GEMM: C[M,N] = A[M,K] @ Bt[N,K]^T + bias, bf16 MFMA ----------------
// 4-wave 128xTN tile (round-3 proven) — used for skinny-N shapes.
template <int MODE, int TN>
__global__ __launch_bounds__(256) void gemm_tn(const u16* __restrict__ A, const u16* __restrict__ Bt,
                                               const u16* __restrict__ bias,
                                               const float* __restrict__ resid_in, float* __restrict__ resid_out,
                                               void* __restrict__ outp, int M, int N, int K,
                                               const int* __restrict__ flagp) {
  constexpr int NI = TN / 32;
  __shared__ __align__(16) u16 As[128 * 64];
  __shared__ __align__(16) u16 Bs[TN * 64];

  int nwg = gridDim.x * gridDim.y;
  int bid = blockIdx.y * gridDim.x + blockIdx.x;
  int chunk = nwg >> 3;
  int s = (bid & 7) * chunk + (bid >> 3);
  int bx = s % gridDim.x, by = s / gridDim.x;

  int n0 = bx * TN, m0 = by * 128;
  int tid = threadIdx.x;
  int lane = tid & 63, w = tid >> 6;
  int wm = w & 1, wn = w >> 1;
  int quad = lane >> 4, l15 = lane & 15;
  int sw = l15 & 7;
  int flag = (MODE == 3) ? *flagp : 0;
  f32x4 acc[4][NI];
  #pragma unroll
  for (int i = 0; i < 4; i++)
    #pragma unroll
    for (int j = 0; j < NI; j++) acc[i][j] = (f32x4){0.f, 0.f, 0.f, 0.f};

  int srow8 = lane >> 3;
  int scol = ((lane & 7) ^ srow8) * 8;
  const u16* Abase = A + (size_t)(m0 + srow8) * K + scol;
  const u16* Bbase = Bt + (size_t)(n0 + srow8) * K + scol;

  for (int k0 = 0; k0 < K; k0 += 64) {
    #pragma unroll
    for (int j = 0; j < 4; ++j) {
      int r0 = (w * 4 + j) * 8;
      async_load16(Abase + (size_t)r0 * K + k0, &As[r0 * 64]);
    }
    #pragma unroll
    for (int j = 0; j < TN / 32; ++j) {
      int r0 = (w * (TN / 32) + j) * 8;
      async_load16(Bbase + (size_t)r0 * K + k0, &Bs[r0 * 64]);
    }
    __syncthreads();
    #pragma unroll
    for (int kk = 0; kk < 64; kk += 32) {
      int cbase = (kk >> 3) + quad;
      int slot = (cbase ^ sw) << 3;
      bf16x8 af[4], bfr[NI];
      #pragma unroll
      for (int i = 0; i < 4; i++)
        af[i] = *(const bf16x8*)&As[(wm * 64 + i * 16 + l15) * 64 + slot];
      #pragma unroll
      for (int j = 0; j < NI; j++)
        bfr[j] = *(const bf16x8*)&Bs[(wn * (TN / 2) + j * 16 + l15) * 64 + slot];
      #pragma unroll
      for (int mi = 0; mi < 4; mi++)
        #pragma unroll
        for (int ni = 0; ni < NI; ni++)
          acc[mi][ni] = __builtin_amdgcn_mfma_f32_16x16x32_bf16(af[mi], bfr[ni], acc[mi][ni], 0, 0, 0);
    }
    __syncthreads();
  }

  int col_base = n0 + wn * (TN / 2), row_base = m0 + wm * 64;
  #pragma unroll
  for (int mi = 0; mi < 4; mi++) {
    #pragma unroll
    for (int ni = 0; ni < NI; ni++) {
      int col = col_base + ni * 16 + l15;
      float bv = bf2f(bias[col]);
      #pragma unroll
      for (int r = 0; r < 4; r++) {
        int row = row_base + mi * 16 + quad * 4 + r;
        float vv = acc[mi][ni][r] + bv;
        size_t idx = (size_t)row * N + col;
        if (MODE == 0) ((u16*)outp)[idx] = f2bf(vv);
        else if (MODE == 1) resid_out[idx] = resid_in[idx] + vv;
        else if (MODE == 2) ((u16*)outp)[idx] = f2bf(gelu_exact(vv));
        else {
          float ov = resid_in[idx] + vv;
          if (flag) ((u16*)outp)[idx] = f2bf(ov);
          else ((float*)outp)[idx] = ov;
        }
      }
    }
  }
}

// ---------------- WIDE TN GEMM: 256x128 tile, 8 waves (proven round 8) ----------------
template <int MODE>
__global__ __launch_bounds__(512) void gemm_wide(const u16* __restrict__ A, const u16* __restrict__ Bt,
                                                 const u16* __restrict__ bias,
                                                 void* __restrict__ outp, int M, int N, int K) {
  __shared__ __align__(16) u16 As[256 * 64];
  __shared__ __align__(16) u16 Bs[128 * 64];

  int nwg = gridDim.x * gridDim.y;
  int bid = blockIdx.y * gridDim.x + blockIdx.x;
  int chunk = nwg >> 3;
  int s = (bid & 7) * chunk + (bid >> 3);
  int bx = s % gridDim.x, by = s / gridDim.x;

  int n0 = bx * 128, m0 = by * 256;
  int tid = threadIdx.x;
  int lane = tid & 63, w = tid >> 6;     // w in 0..7
  int wm = w & 3, wn = w >> 2;           // 4 (m) x 2 (n) waves; per-wave out 64x64
  int quad = lane >> 4, l15 = lane & 15;
  int sw = l15 & 7;
  f32x4 acc[4][4];
  #pragma unroll
  for (int i = 0; i < 4; i++)
    #pragma unroll
    for (int j = 0; j < 4; j++) acc[i][j] = (f32x4){0.f, 0.f, 0.f, 0.f};

  int srow8 = lane >> 3;
  int scol = ((lane & 7) ^ srow8) * 8;
  const u16* Abase = A + (size_t)(m0 + srow8) * K + scol;
  const u16* Bbase = Bt + (size_t)(n0 + srow8) * K + scol;

  for (int k0 = 0; k0 < K; k0 += 64) {
    #pragma unroll
    for (int j = 0; j < 4; ++j) {                  // A: 256 rows = 32 groups / 8 waves
      int r0 = (w * 4 + j) * 8;
      async_load16(Abase + (size_t)r0 * K + k0, &As[r0 * 64]);
    }
    #pragma unroll
    for (int j = 0; j < 2; ++j) {                  // B: 128 rows = 16 groups / 8 waves
      int r0 = (w * 2 + j) * 8;
      async_load16(Bbase + (size_t)r0 * K + k0, &Bs[r0 * 64]);
    }
    __syncthreads();
    #pragma unroll
    for (int kk = 0; kk < 64; kk += 32) {
      int cbase = (kk >> 3) + quad;
      int slot = (cbase ^ sw) << 3;
      bf16x8 af[4], bfr[4];
      #pragma unroll
      for (int i = 0; i < 4; i++)
        af[i] = *(const bf16x8*)&As[(wm * 64 + i * 16 + l15) * 64 + slot];
      #pragma unroll
      for (int j = 0; j < 4; j++)
        bfr[j] = *(const bf16x8*)&Bs[(wn * 64 + j * 16 + l15) * 64 + slot];
      #pragma unroll
      for (int mi = 0; mi < 4; mi++)
        #pragma unroll
        for (int ni = 0; ni < 4; ni++)
          acc[mi][ni] = __builtin_amdgcn_mfma_f32_16x16x32_bf16(af[mi], bfr[ni], acc[mi][ni], 0, 0, 0);
    }
    __syncthreads();
  }

  int col_base = n0 + wn * 64, row_base = m0 + wm * 64;
  #pragma unroll
  for (int mi = 0; mi < 4; mi++) {
    #pragma unroll
    for (int ni = 0; ni < 4; ni++) {
      int col = col_base + ni * 16 + l15;
      float bv = bf2f(bias[col]);
      #pragma unroll
      for (int r = 0; r < 4; r++) {
        int row = row_base + mi * 16 + quad * 4 + r;
        float vv = acc[mi][ni][r] + bv;
        size_t idx = (size_t)row * N + col;
        if (MODE == 0) ((u16*)outp)[idx] = f2bf(vv);
        else ((u16*)outp)[idx] = f2bf(gelu_exact(vv));
      }
    }
  }
}

// ---------------- MFMA flash attention, HD=64, QBLK=64, KV-PAIR unrolled ----------------
// Round-8 base (numerics-proven: absmax 0.03125) with tiles processed in pairs
// (t, t+1): Ks[2]/Vt[2] buffers, 2 barriers per 128 keys instead of 4, ONE
// K-DMA wait per pair, and tile-B's LDS reads pipeline behind tile-A's compute
// with no intervening wait. Per-tile op sequence (QK^T -> scale -> mask ->
// online softmax -> PV, ascending s0) is IDENTICAL to the per-64 loop ->
// numerically identical. Manual vmcnt = #V-loads just issued (K DMAs oldest,
// r4/r8-proven counting); all branches wave-uniform. LDS 40KB -> 4 blocks/CU
// (grid 1024 = 4/CU). Slot remap keeps a head's 16 q-tiles on one XCD.
__global__ __launch_bounds__(256) void attn_mfma(const u16* __restrict__ Q, const u16* __restrict__ K,
                                                 const u16* __restrict__ V, u16* __restrict__ O,
                                                 int T, int S, int qstride, int kstride, int causal) {
  int slot = blockIdx.y * gridDim.x + blockIdx.x;  // grid (16,64) -> 0..1023
  int c = slot & 7, u = slot >> 3;
  int bh = c * 8 + (u >> 4);      // 8 heads per XCD, consecutive slots same head
  int qi = u & 15;                // all 16 q-tiles of the head back-to-back
  int b = bh >> 4, h = bh & 15;
  int qt = qi * 64;

  const u16* Qb = Q + (size_t)b * T * qstride + h * 64;
  const u16* Kb = K + (size_t)b * S * kstride + h * 64;
  const u16* Vb = V + (size_t)b * S * kstride + h * 64;
  u16* Ob = O + (size_t)b * T * 1024 + h * 64;

  int tid = threadIdx.x, lane = tid & 63, w = tid >> 6;
  int quad = lane >> 4, l15 = lane & 15;

  __shared__ __align__(16) u16 Ks[2][64 * 64];
  __shared__ __align__(16) u16 Vt[2][64 * 64];
  __shared__ __align__(16) u16 Ps[4][16 * 64];

  int srow8 = lane >> 3;
  int scol = ((lane & 7) ^ srow8) * 8;

  int nk = causal ? (qi + 1) * 64 : S;

  // ---- prologue: Q DMA -> Ks[0]; V(0) and V(64) -> regs ----
  #pragma unroll
  for (int j = 0; j < 2; ++j) {
    int r0 = (w * 2 + j) * 8;
    async_load16(Qb + (size_t)(qt + r0 + srow8) * qstride + scol, &Ks[0][r0 * 64]);
  }
  asm volatile("" ::: "memory");
  uint4 vA0 = *(const uint4*)&Vb[(size_t)lane * kstride + w * 16];
  uint4 vA1 = *(const uint4*)&Vb[(size_t)lane * kstride + w * 16 + 8];
  uint4 vB0, vB1;
  if (nk > 64) {
    vB0 = *(const uint4*)&Vb[(size_t)(64 + lane) * kstride + w * 16];
    vB1 = *(const uint4*)&Vb[(size_t)(64 + lane) * kstride + w * 16 + 8];
    asm volatile("s_waitcnt vmcnt(4)" ::: "memory");  // Q landed; 4 V loads flying
  } else {
    asm volatile("s_waitcnt vmcnt(2)" ::: "memory");  // Q landed; 2 V loads flying
  }
  __builtin_amdgcn_s_barrier();

  int qrow = w * 16 + l15;
  bf16x8 qfrag[2];
  #pragma unroll
  for (int cc = 0; cc < 2; ++cc)
    qfrag[cc] = *(const bf16x8*)&Ks[0][qrow * 64 + (((cc * 4 + quad) ^ (l15 & 7)) << 3)];
  asm volatile("s_waitcnt lgkmcnt(0)" ::: "memory");  // qfrag in regs before Ks[0] overwrite

  float m_i[4], l_i[4];
  f32x4 oacc[4];
  #pragma unroll
  for (int r = 0; r < 4; ++r) { m_i[r] = -1e30f; l_i[r] = 0.f; }
  #pragma unroll
  for (int ni = 0; ni < 4; ++ni) oacc[ni] = (f32x4){0.f, 0.f, 0.f, 0.f};

  int tg0 = qt + w * 16 + quad * 4;

  for (int s0 = 0; s0 < nk; s0 += 128) {
    int hasB = (s0 + 64) < nk;
    __builtin_amdgcn_s_barrier();  // prev pair fully consumed by all waves
    // K DMAs for the pair
    #pragma unroll
    for (int j = 0; j < 2; ++j) {
      int r0 = (w * 2 + j) * 8;
      async_load16(Kb + (size_t)(s0 + r0 + srow8) * kstride + scol, &Ks[0][r0 * 64]);
    }
    if (hasB) {
      #pragma unroll
      for (int j = 0; j < 2; ++j) {
        int r0 = (w * 2 + j) * 8;
        async_load16(Kb + (size_t)(s0 + 64 + r0 + srow8) * kstride + scol, &Ks[1][r0 * 64]);
      }
    }
    asm volatile("" ::: "memory");
    // V transpose stores (compiler waits the V regs; K DMAs are newer, stay in flight)
    {
      union { uint4 u4[2]; u16 e[16]; } vv; vv.u4[0] = vA0; vv.u4[1] = vA1;
      #pragma unroll
      for (int j = 0; j < 16; ++j) {
        int d = w * 16 + j;
        Vt[0][d * 64 + ((((lane >> 3) ^ (j & 7)) << 3) | (lane & 7))] = vv.e[j];
      }
    }
    if (hasB) {
      union { uint4 u4[2]; u16 e[16]; } vv; vv.u4[0] = vB0; vv.u4[1] = vB1;
      #pragma unroll
      for (int j = 0; j < 16; ++j) {
        int d = w * 16 + j;
        Vt[1][d * 64 + ((((lane >> 3) ^ (j & 7)) << 3) | (lane & 7))] = vv.e[j];
      }
    }
    // prefetch next pair's V
    int nA = (s0 + 128) < nk, nB = (s0 + 192) < nk;
    if (nA) {
      vA0 = *(const uint4*)&Vb[(size_t)(s0 + 128 + lane) * kstride + w * 16];
      vA1 = *(const uint4*)&Vb[(size_t)(s0 + 128 + lane) * kstride + w * 16 + 8];
    }
    if (nB) {
      vB0 = *(const uint4*)&Vb[(size_t)(s0 + 192 + lane) * kstride + w * 16];
      vB1 = *(const uint4*)&Vb[(size_t)(s0 + 192 + lane) * kstride + w * 16 + 8];
    }
    // wait for the pair's K DMAs (oldest); leave just-issued V loads in flight
    if (nB)       { asm volatile("s_waitcnt vmcnt(4)" ::: "memory"); }
    else if (nA)  { asm volatile("s_waitcnt vmcnt(2)" ::: "memory"); }
    else          { asm volatile("s_waitcnt vmcnt(0)" ::: "memory"); }
    asm volatile("s_waitcnt lgkmcnt(0)" ::: "memory");  // Vt stores committed
    __builtin_amdgcn_s_barrier();

    // ---- compute tiles of the pair, in order (numerics identical to per-64 loop) ----
    #pragma unroll
    for (int half = 0; half < 2; ++half) {
      if (half == 1 && !hasB) break;
      int sbase = s0 + half * 64;

      f32x4 sacc[4];
      #pragma unroll
      for (int ni = 0; ni < 4; ++ni) sacc[ni] = (f32x4){0.f, 0.f, 0.f, 0.f};
      __builtin_amdgcn_s_setprio(1);
      #pragma unroll
      for (int cc = 0; cc < 2; ++cc) {
        #pragma unroll
        for (int ni = 0; ni < 4; ++ni) {
          bf16x8 kf = *(const bf16x8*)&Ks[half][(ni * 16 + l15) * 64 + (((cc * 4 + quad) ^ (l15 & 7)) << 3)];
          sacc[ni] = __builtin_amdgcn_mfma_f32_16x16x32_bf16(qfrag[cc], kf, sacc[ni], 0, 0, 0);
        }
      }
      __builtin_amdgcn_s_setprio(0);

      #pragma unroll
      for (int ni = 0; ni < 4; ++ni)
        #pragma unroll
        for (int r = 0; r < 4; ++r) sacc[ni][r] *= 0.125f;
      if (causal && sbase + 63 > qt + w * 16) {  // wave-uniform: only diagonal tile
        #pragma unroll
        for (int ni = 0; ni < 4; ++ni) {
          int key = sbase + ni * 16 + l15;
          #pragma unroll
          for (int r = 0; r < 4; ++r)
            if (key > tg0 + r) sacc[ni][r] = -1e30f;
        }
      }

      // ---- online softmax ----
      float mnew[4], alpha[4], psum[4];
      #pragma unroll
      for (int r = 0; r < 4; ++r) {
        float mx = fmaxf(fmaxf(sacc[0][r], sacc[1][r]), fmaxf(sacc[2][r], sacc[3][r]));
        #pragma unroll
        for (int off = 1; off < 16; off <<= 1) mx = fmaxf(mx, __shfl_xor(mx, off));
        mnew[r] = fmaxf(m_i[r], mx);
        alpha[r] = __expf(m_i[r] - mnew[r]);
        m_i[r] = mnew[r];
        psum[r] = 0.f;
      }
      #pragma unroll
      for (int ni = 0; ni < 4; ++ni) {
        #pragma unroll
        for (int r = 0; r < 4; ++r) {
          float p = __expf(sacc[ni][r] - mnew[r]);
          psum[r] += p;
          int row = quad * 4 + r;
          int blk = (ni * 2 + (l15 >> 3)) ^ (row & 7);
          Ps[w][row * 64 + (blk << 3) + (l15 & 7)] = f2bf(p);
        }
      }
      #pragma unroll
      for (int r = 0; r < 4; ++r) {
        float ps = psum[r];
        #pragma unroll
        for (int off = 1; off < 16; off <<= 1) ps += __shfl_xor(ps, off);
        l_i[r] = l_i[r] * alpha[r] + ps;
      }

      // ---- PV ----
      bf16x8 pfrag[2];
      #pragma unroll
      for (int cc = 0; cc < 2; ++cc)
        pfrag[cc] = *(const bf16x8*)&Ps[w][l15 * 64 + (((cc * 4 + quad) ^ (l15 & 7)) << 3)];
      #pragma unroll
      for (int ni = 0; ni < 4; ++ni)
        #pragma unroll
        for (int r = 0; r < 4; ++r) oacc[ni][r] *= alpha[r];
      __builtin_amdgcn_s_setprio(1);
      #pragma unroll
      for (int cc = 0; cc < 2; ++cc) {
        #pragma unroll
        for (int ni = 0; ni < 4; ++ni) {
          bf16x8 vf = *(const bf16x8*)&Vt[half][(ni * 16 + l15) * 64 + (((cc * 4 + quad) ^ (l15 & 7)) << 3)];
          oacc[ni] = __builtin_amdgcn_mfma_f32_16x16x32_bf16(pfrag[cc], vf, oacc[ni], 0, 0, 0);
        }
      }
      __builtin_amdgcn_s_setprio(0);
    }
  }

  #pragma unroll
  for (int ni = 0; ni < 4; ++ni) {
    #pragma unroll
    for (int r = 0; r < 4; ++r) {
      int t = tg0 + r;
      int d = ni * 16 + l15;
      Ob[(size_t)t * 1024 + d] = f2bf(oacc[ni][r] / l_i[r]);
    }
  }
}

extern "C" void kernel_launch(void* const* d_in, const int* in_sizes, int n_in,
                              void* d_out, int out_size, void* d_ws, size_t ws_size,
                              hipStream_t stream) {
  const void* x_in   = d_in[0];
  const void* enc_in = d_in[1];
  const void* ln1_w = d_in[4];  const void* ln1_b = d_in[5];
  const void* qkv_w = d_in[6];  const void* qkv_b = d_in[7];
  const void* proj_w = d_in[8]; const void* proj_b = d_in[9];
  const void* ln2_w = d_in[10]; const void* ln2_b = d_in[11];
  const void* q_w = d_in[12];   const void* q_b = d_in[13];
  const void* k_w = d_in[14];   const void* k_b = d_in[15];
  const void* v_w = d_in[16];   const void* v_b = d_in[17];
  const void* out_w = d_in[18]; const void* out_b = d_in[19];
  const void* ln3_w = d_in[20]; const void* ln3_b = d_in[21];
  const void* mlp1_w = d_in[22]; const void* mlp1_b = d_in[23];
  const void* mlp2_w = d_in[24]; const void* mlp2_b = d_in[25];

  char* ws = (char*)d_ws;
  size_t off = 0;
  auto alloc = [&](size_t bytes) { char* p = ws + off; off += (bytes + 255) & ~(size_t)255; return p; };
  float* xf   = (float*)alloc(4096ull * 1024 * 4);
  u16* hb     = (u16*)alloc(4096ull * 1024 * 2);
  u16* big    = (u16*)alloc(4096ull * 4096 * 2);
  u16* wT     = (u16*)alloc(3072ull * 1024 * 2);
  u16* encb   = (u16*)alloc(2304ull * 768 * 2);
  u16* pool   = (u16*)alloc(20480ull * 2);
  int* flag   = (int*)alloc(256);
  (void)ws_size;

  u16* q_bf = big;                            // [4096,1024]
  u16* kv   = big + 4096ull * 1024;           // [2304,2048] interleaved K|V

  u16 *p_ln1w = pool, *p_ln1b = pool + 1024, *p_ln2w = pool + 2048, *p_ln2b = pool + 3072;
  u16 *p_ln3w = pool + 4096, *p_ln3b = pool + 5120;
  u16 *p_qkvb = pool + 6144, *p_projb = pool + 9216, *p_qb = pool + 10240, *p_kb = pool + 11264;
  u16 *p_vb = pool + 12288, *p_outb = pool + 13312, *p_m1b = pool + 14336, *p_m2b = pool + 18432;

  // ---- dtype sniff + input conversion ----
  sniff_kernel<<<1, 64, 0, stream>>>((const u16*)x_in, flag);
  in2f32_kernel<<<4096, 256, 0, stream>>>(x_in, xf, 1048576, flag);
  in2bf_kernel<<<1728, 256, 0, stream>>>(enc_in, encb, 442368, flag);
  small2bf_kernel<<<19, 256, 0, stream>>>(ln1_w, ln1_b, ln2_w, ln2_b, ln3_w, ln3_b,
                                          qkv_b, proj_b, q_b, k_b, v_b, out_b,
                                          mlp1_b, mlp2_b, pool, flag);

  // ---- self-attention block ----
  ln_kernel<<<4096, 256, 0, stream>>>(xf, p_ln1w, p_ln1b, hb);
  transpose_k<<<dim3(96, 32), 256, 0, stream>>>(qkv_w, wT, 1024, 3072, flag);
  gemm_wide<0><<<dim3(24, 16), 512, 0, stream>>>(hb, wT, p_qkvb, big, 4096, 3072, 1024);
  attn_mfma<<<dim3(16, 64), 256, 0, stream>>>(big, big + 1024, big + 2048, hb, 1024, 1024, 3072, 3072, 1);
  transpose_k<<<dim3(32, 32), 256, 0, stream>>>(proj_w, wT, 1024, 1024, flag);
  gemm_tn<1, 64><<<dim3(16, 32), 256, 0, stream>>>(hb, wT, p_projb, xf, xf, nullptr, 4096, 1024, 1024, flag);

  // ---- cross-attention block ----
  ln_kernel<<<4096, 256, 0, stream>>>(xf, p_ln2w, p_ln2b, hb);
  transpose_k<<<dim3(32, 32), 256, 0, stream>>>(q_w, wT, 1024, 1024, flag);
  gemm_tn<0, 64><<<dim3(16, 32), 256, 0, stream>>>(hb, wT, p_qb, nullptr, nullptr, q_bf, 4096, 1024, 1024, flag);
  // fused K|V projection: Bt = [k_w^T ; v_w^T] (contiguous rows), bias = p_kb|p_vb
  // (adjacent in pool), output interleaved [2304][2048]; attn reads kstride=2048.
  transpose_k<<<dim3(32, 24), 256, 0, stream>>>(k_w, wT, 768, 1024, flag);
  transpose_k<<<dim3(32, 24), 256, 0, stream>>>(v_w, wT + 1024ull * 768, 768, 1024, flag);
  gemm_tn<0, 64><<<dim3(32, 18), 256, 0, stream>>>(encb, wT, p_kb, nullptr, nullptr, kv, 2304, 2048, 768, flag);
  attn_mfma<<<dim3(16, 64), 256, 0, stream>>>(q_bf, kv, kv + 1024, hb, 1024, 576, 1024, 2048, 0);
  transpose_k<<<dim3(32, 32), 256, 0, stream>>>(out_w, wT, 1024, 1024, flag);
  gemm_tn<1, 64><<<dim3(16, 32), 256, 0, stream>>>(hb, wT, p_outb, xf, xf, nullptr, 4096, 1024, 1024, flag);

  // ---- MLP block ----
  ln_kernel<<<4096, 256, 0, stream>>>(xf, p_ln3w, p_ln3b, hb);
  transpose_k<<<dim3(128, 32), 256, 0, stream>>>(mlp1_w, wT, 1024, 4096, flag);
  gemm_wide<2><<<dim3(32, 16), 512, 0, stream>>>(hb, wT, p_m1b, big, 4096, 4096, 1024);
  transpose_k<<<dim3(32, 128), 256, 0, stream>>>(mlp2_w, wT, 4096, 1024, flag);
  gemm_tn<3, 64><<<dim3(16, 32), 256, 0, stream>>>(big, wT, p_m2b, xf, nullptr, d_out, 4096, 1024, 4096, flag);
}